// Round 1
// baseline (6791.079 us; speedup 1.0000x reference)
//
#include <hip/hip_runtime.h>

#define NN 50000
#define EE 600000
#define DD 128
#define GG 256
#define LL 5
#define OO 10
#define BN_EPS 1e-5f

// ---------------- count / inv ----------------
__global__ void count_kernel(const int* __restrict__ batch, float* __restrict__ counts) {
    int n = blockIdx.x * 256 + threadIdx.x;
    if (n < NN) atomicAdd(&counts[batch[n]], 1.0f);
}

__global__ void inv_kernel(const float* __restrict__ counts, float* __restrict__ inv) {
    int g = threadIdx.x;
    if (g < GG) inv[g] = 1.0f / fmaxf(counts[g], 1.0f);
}

// ---------------- edge aggregation ----------------
// 32 threads per edge, each thread handles 4 contiguous features (float4).
__launch_bounds__(256)
__global__ void edge_aggr(const float* __restrict__ x,
                          const int* __restrict__ ei,
                          const int* __restrict__ eattr,
                          const float* __restrict__ bond,   // [3][8][D] for this layer
                          float* __restrict__ aggr) {
    int t = blockIdx.x * 256 + threadIdx.x;
    int e = t >> 5;
    if (e >= EE) return;
    int d = (t & 31) * 4;
    int src = ei[e];
    int dst = ei[EE + e];
    int a0 = eattr[e * 3 + 0];
    int a1 = eattr[e * 3 + 1];
    int a2 = eattr[e * 3 + 2];
    float4 xv = *(const float4*)&x[(size_t)src * DD + d];
    float4 b0 = *(const float4*)&bond[(0 * 8 + a0) * DD + d];
    float4 b1 = *(const float4*)&bond[(1 * 8 + a1) * DD + d];
    float4 b2 = *(const float4*)&bond[(2 * 8 + a2) * DD + d];
    float m0 = fmaxf(xv.x + b0.x + b1.x + b2.x, 0.0f);
    float m1 = fmaxf(xv.y + b0.y + b1.y + b2.y, 0.0f);
    float m2 = fmaxf(xv.z + b0.z + b1.z + b2.z, 0.0f);
    float m3 = fmaxf(xv.w + b0.w + b1.w + b2.w, 0.0f);
    float* p = &aggr[(size_t)dst * DD + d];
    atomicAdd(p + 0, m0);
    atomicAdd(p + 1, m1);
    atomicAdd(p + 2, m2);
    atomicAdd(p + 3, m3);
}

// ---------------- fused GEMM + bias + BN + ReLU ----------------
// Out[n, :] = relu(bn((A[n,:] (+ Add[n,:])) @ W + b))
// Block: 256 threads, 32 rows. Full W (128x128, 64KB) + A-tile (16KB) in LDS.
__launch_bounds__(256)
__global__ void gemm_bn_relu(const float* __restrict__ A,
                             const float* __restrict__ Add,   // may be null
                             const float* __restrict__ W,
                             const float* __restrict__ bias,
                             const float* __restrict__ gamma,
                             const float* __restrict__ beta,
                             const float* __restrict__ mean,
                             const float* __restrict__ var,
                             float* __restrict__ Out) {
    __shared__ float Ws[DD * DD];
    __shared__ float As[32 * DD];
    const int tid  = threadIdx.x;
    const int row0 = blockIdx.x * 32;

    // Load W: 16384 floats, 64 per thread (16 x float4)
    for (int i = tid * 4; i < DD * DD; i += 256 * 4) {
        *(float4*)&Ws[i] = *(const float4*)&W[i];
    }
    // Load A tile (+ optional addend): 4096 floats
    for (int i = tid * 4; i < 32 * DD; i += 256 * 4) {
        int r = row0 + (i >> 7);
        float4 v = make_float4(0.f, 0.f, 0.f, 0.f);
        if (r < NN) {
            v = *(const float4*)&A[(size_t)r * DD + (i & 127)];
            if (Add) {
                float4 w = *(const float4*)&Add[(size_t)r * DD + (i & 127)];
                v.x += w.x; v.y += w.y; v.z += w.z; v.w += w.w;
            }
        }
        *(float4*)&As[i] = v;
    }
    __syncthreads();

    const int r  = tid >> 3;          // 0..31
    const int c0 = (tid & 7) * 16;    // 0,16,...,112
    float acc[16];
#pragma unroll
    for (int j = 0; j < 16; ++j) acc[j] = 0.f;

    for (int k = 0; k < DD; ++k) {
        float a = As[r * DD + k];
#pragma unroll
        for (int j = 0; j < 16; ++j)
            acc[j] = fmaf(a, Ws[k * DD + c0 + j], acc[j]);
    }

    int row = row0 + r;
    if (row < NN) {
#pragma unroll
        for (int j = 0; j < 16; ++j) {
            int c = c0 + j;
            float scale = gamma[c] * rsqrtf(var[c] + BN_EPS);
            float v = (acc[j] + bias[c] - mean[c]) * scale + beta[c];
            Out[(size_t)row * DD + c] = fmaxf(v, 0.f);
        }
    }
}

// ---------------- pooling (segment sum via atomics) ----------------
__launch_bounds__(256)
__global__ void pool_add(const float* __restrict__ x, const int* __restrict__ batch,
                         float* __restrict__ pooled) {
    int t = blockIdx.x * 256 + threadIdx.x;
    int n = t >> 5;
    if (n >= NN) return;
    int d = (t & 31) * 4;
    int g = batch[n];
    float4 v = *(const float4*)&x[(size_t)n * DD + d];
    float* p = &pooled[(size_t)g * DD + d];
    atomicAdd(p + 0, v.x);
    atomicAdd(p + 1, v.y);
    atomicAdd(p + 2, v.z);
    atomicAdd(p + 3, v.w);
}

// ---------------- head: out[g,o] += inv[g]*pooled[g,:]@fcw[:,o] + fcb[o] ----------------
__global__ void head_kernel(const float* __restrict__ pooled, const float* __restrict__ inv,
                            const float* __restrict__ fcw, const float* __restrict__ fcb,
                            float* __restrict__ out) {
    int t = blockIdx.x * 256 + threadIdx.x;
    if (t >= GG * OO) return;
    int g = t / OO, o = t % OO;
    float s = 0.f;
    for (int d = 0; d < DD; ++d)
        s = fmaf(pooled[g * DD + d], fcw[d * OO + o], s);
    out[t] += s * inv[g] + fcb[o];
}

extern "C" void kernel_launch(void* const* d_in, const int* in_sizes, int n_in,
                              void* d_out, int out_size, void* d_ws, size_t ws_size,
                              hipStream_t stream) {
    const float* x_in    = (const float*)d_in[0];
    const int*   ei      = (const int*)d_in[1];
    const int*   eattr   = (const int*)d_in[2];
    const int*   batch   = (const int*)d_in[3];
    const float* bond    = (const float*)d_in[4];
    const float* conv_w1 = (const float*)d_in[5];
    const float* conv_b1 = (const float*)d_in[6];
    const float* cbg     = (const float*)d_in[7];
    const float* cbb     = (const float*)d_in[8];
    const float* cbm     = (const float*)d_in[9];
    const float* cbv     = (const float*)d_in[10];
    const float* conv_w2 = (const float*)d_in[11];
    const float* conv_b2 = (const float*)d_in[12];
    const float* bg      = (const float*)d_in[13];
    const float* bb      = (const float*)d_in[14];
    const float* bm      = (const float*)d_in[15];
    const float* bv      = (const float*)d_in[16];
    const float* fcw     = (const float*)d_in[17];
    const float* fcb     = (const float*)d_in[18];
    float* out = (float*)d_out;

    float* ws     = (float*)d_ws;
    float* cur    = ws;                          // N*D
    float* aggr   = cur + (size_t)NN * DD;       // N*D
    float* h1     = aggr + (size_t)NN * DD;      // N*D
    float* pooled = h1 + (size_t)NN * DD;        // G*D
    float* counts = pooled + (size_t)GG * DD;    // G
    float* inv    = counts + GG;                 // G

    hipMemcpyAsync(cur, x_in, (size_t)NN * DD * sizeof(float),
                   hipMemcpyDeviceToDevice, stream);
    hipMemsetAsync(counts, 0, GG * sizeof(float), stream);
    hipMemsetAsync(out, 0, (size_t)GG * OO * sizeof(float), stream);

    count_kernel<<<(NN + 255) / 256, 256, 0, stream>>>(batch, counts);
    inv_kernel<<<1, 256, 0, stream>>>(counts, inv);

    // layer-0 pooled output (input x)
    hipMemsetAsync(pooled, 0, (size_t)GG * DD * sizeof(float), stream);
    pool_add<<<(NN * 32 + 255) / 256, 256, 0, stream>>>(cur, batch, pooled);
    head_kernel<<<(GG * OO + 255) / 256, 256, 0, stream>>>(pooled, inv, fcw, fcb, out);

    const int gemm_blocks = (NN + 31) / 32;
    for (int i = 0; i < LL; ++i) {
        hipMemsetAsync(aggr, 0, (size_t)NN * DD * sizeof(float), stream);
        edge_aggr<<<(EE * 32 + 255) / 256, 256, 0, stream>>>(
            cur, ei, eattr, bond + (size_t)i * 3 * 8 * DD, aggr);
        gemm_bn_relu<<<gemm_blocks, 256, 0, stream>>>(
            cur, aggr,
            conv_w1 + (size_t)i * DD * DD, conv_b1 + (size_t)i * DD,
            cbg + (size_t)i * DD, cbb + (size_t)i * DD,
            cbm + (size_t)i * DD, cbv + (size_t)i * DD, h1);
        gemm_bn_relu<<<gemm_blocks, 256, 0, stream>>>(
            h1, nullptr,
            conv_w2 + (size_t)i * DD * DD, conv_b2 + (size_t)i * DD,
            bg + (size_t)i * DD, bb + (size_t)i * DD,
            bm + (size_t)i * DD, bv + (size_t)i * DD, cur);
        hipMemsetAsync(pooled, 0, (size_t)GG * DD * sizeof(float), stream);
        pool_add<<<(NN * 32 + 255) / 256, 256, 0, stream>>>(cur, batch, pooled);
        head_kernel<<<(GG * OO + 255) / 256, 256, 0, stream>>>(
            pooled, inv, fcw + (size_t)(i + 1) * DD * OO, fcb + (size_t)(i + 1) * OO, out);
    }
}

// Round 2
// 1225.297 us; speedup vs baseline: 5.5424x; 5.5424x over previous
//
#include <hip/hip_runtime.h>

#define NN 50000
#define EE 600000
#define DD 128
#define GG 256
#define LL 5
#define OO 10
#define BN_EPS 1e-5f

// ---------------- degree histogram ----------------
__launch_bounds__(256)
__global__ void deg_kernel(const int* __restrict__ ei, int* __restrict__ deg) {
    int e = blockIdx.x * 256 + threadIdx.x;
    if (e < EE) atomicAdd(&deg[ei[EE + e]], 1);
}

__launch_bounds__(256)
__global__ void gcount_kernel(const int* __restrict__ batch, int* __restrict__ gcnt) {
    int n = blockIdx.x * 256 + threadIdx.x;
    if (n < NN) atomicAdd(&gcnt[batch[n]], 1);
}

// ---------------- exclusive scan over node degrees (single block) ----------------
__launch_bounds__(1024)
__global__ void scan_off(const int* __restrict__ deg, int* __restrict__ off,
                         int* __restrict__ epos) {
    __shared__ int part[1024];
    int t = threadIdx.x;
    const int C = (NN + 1023) / 1024;
    int lo = t * C, hi = lo + C;
    if (hi > NN) hi = NN;
    if (lo > NN) lo = NN;
    int s = 0;
    for (int i = lo; i < hi; ++i) s += deg[i];
    part[t] = s;
    __syncthreads();
    for (int d = 1; d < 1024; d <<= 1) {
        int v = (t >= d) ? part[t - d] : 0;
        __syncthreads();
        part[t] += v;
        __syncthreads();
    }
    int run = (t == 0) ? 0 : part[t - 1];
    for (int i = lo; i < hi; ++i) { off[i] = run; epos[i] = run; run += deg[i]; }
    if (t == 1023) off[NN] = part[1023];
}

// ---------------- graph offsets + inv counts (single block, G=256) ----------------
__launch_bounds__(256)
__global__ void gscan(const int* __restrict__ gcnt, int* __restrict__ goff,
                      float* __restrict__ inv) {
    __shared__ int part[GG];
    int t = threadIdx.x;
    int c = gcnt[t];
    part[t] = c;
    __syncthreads();
    for (int d = 1; d < GG; d <<= 1) {
        int v = (t >= d) ? part[t - d] : 0;
        __syncthreads();
        part[t] += v;
        __syncthreads();
    }
    goff[t] = part[t] - c;
    if (t == GG - 1) goff[GG] = part[GG - 1];
    inv[t] = 1.0f / fmaxf((float)c, 1.0f);
}

// ---------------- scatter edges into CSR (by dst). payload: src|a0|a1|a2 ----------------
__launch_bounds__(256)
__global__ void scatter_edges(const int* __restrict__ ei, const int* __restrict__ eattr,
                              int* __restrict__ epos, unsigned* __restrict__ e_info) {
    int e = blockIdx.x * 256 + threadIdx.x;
    if (e >= EE) return;
    int dst = ei[EE + e];
    int pos = atomicAdd(&epos[dst], 1);
    unsigned pk = (unsigned)ei[e] | ((unsigned)eattr[e * 3 + 0] << 16)
                | ((unsigned)eattr[e * 3 + 1] << 19) | ((unsigned)eattr[e * 3 + 2] << 22);
    e_info[pos] = pk;
}

// ---------------- CSR aggregation: one wave per node, no atomics ----------------
__launch_bounds__(256)
__global__ void aggr_csr(const float* __restrict__ x, const int* __restrict__ off,
                         const unsigned* __restrict__ e_info, const float* __restrict__ bond,
                         float* __restrict__ aggr) {
    int node = blockIdx.x * 4 + (threadIdx.x >> 6);
    int lane = threadIdx.x & 63;
    if (node >= NN) return;
    int p = off[node], pe = off[node + 1];
    int d = lane * 2;
    float ax = 0.f, ay = 0.f;
    for (; p < pe; ++p) {
        unsigned info = e_info[p];
        int s = info & 0xFFFFu;
        float2 xv = *(const float2*)&x[(size_t)s * DD + d];
        float2 b0 = *(const float2*)&bond[((info >> 16) & 7u) * DD + d];
        float2 b1 = *(const float2*)&bond[(8u + ((info >> 19) & 7u)) * DD + d];
        float2 b2 = *(const float2*)&bond[(16u + ((info >> 22) & 7u)) * DD + d];
        ax += fmaxf(xv.x + b0.x + b1.x + b2.x, 0.f);
        ay += fmaxf(xv.y + b0.y + b1.y + b2.y, 0.f);
    }
    float2 r; r.x = ax; r.y = ay;
    *(float2*)&aggr[(size_t)node * DD + d] = r;
}

// ---------------- fused GEMM + bias + BN + ReLU, 4x4 micro-tile ----------------
// Out[n,:] = relu(bn((A[n,:] (+ Add[n,:])) @ W + b)); W staged in two 64-row chunks.
// LDS = 32KB (Ws chunk) + 16.9KB (As, stride 132) = 48.5KB -> 3 blocks/CU.
__launch_bounds__(256)
__global__ void gemm_bn_relu(const float* __restrict__ A,
                             const float* __restrict__ Add,
                             const float* __restrict__ W,
                             const float* __restrict__ bias,
                             const float* __restrict__ gamma,
                             const float* __restrict__ beta,
                             const float* __restrict__ mean,
                             const float* __restrict__ var,
                             float* __restrict__ Out) {
    __shared__ float Ws[64 * DD];      // one 64-k chunk of W, [k][c]
    __shared__ float As[32 * 132];     // A tile, row-major, padded stride 132
    const int tid  = threadIdx.x;
    const int row0 = blockIdx.x * 32;

    // stage A tile (+ optional addend): 32 rows x 128, float4 coalesced
    for (int i = tid; i < 1024; i += 256) {
        int r = i >> 5, k4 = (i & 31) * 4;
        int row = row0 + r;
        float4 v = make_float4(0.f, 0.f, 0.f, 0.f);
        if (row < NN) {
            v = *(const float4*)&A[(size_t)row * DD + k4];
            if (Add) {
                float4 w = *(const float4*)&Add[(size_t)row * DD + k4];
                v.x += w.x; v.y += w.y; v.z += w.z; v.w += w.w;
            }
        }
        *(float4*)&As[r * 132 + k4] = v;   // 528B row stride: 16B-aligned
    }

    const int rg = tid >> 5, cg = tid & 31;
    const int r0 = rg * 4, c0 = cg * 4;
    float acc[4][4];
#pragma unroll
    for (int j = 0; j < 4; ++j)
#pragma unroll
        for (int q = 0; q < 4; ++q) acc[j][q] = 0.f;

    for (int kc = 0; kc < 2; ++kc) {
        __syncthreads();   // As ready (kc=0) / Ws no longer in use (kc=1)
        for (int i = tid; i < 2048; i += 256)
            *(float4*)&Ws[i * 4] = *(const float4*)&W[(size_t)kc * 64 * DD + i * 4];
        __syncthreads();
        const int kbase = kc * 64;
#pragma unroll 4
        for (int k4 = 0; k4 < 64; k4 += 4) {
            float4 wv0 = *(const float4*)&Ws[(k4 + 0) * DD + c0];
            float4 wv1 = *(const float4*)&Ws[(k4 + 1) * DD + c0];
            float4 wv2 = *(const float4*)&Ws[(k4 + 2) * DD + c0];
            float4 wv3 = *(const float4*)&Ws[(k4 + 3) * DD + c0];
#pragma unroll
            for (int j = 0; j < 4; ++j) {
                float4 a = *(const float4*)&As[(r0 + j) * 132 + kbase + k4];
                acc[j][0] = fmaf(a.x, wv0.x, fmaf(a.y, wv1.x, fmaf(a.z, wv2.x, fmaf(a.w, wv3.x, acc[j][0]))));
                acc[j][1] = fmaf(a.x, wv0.y, fmaf(a.y, wv1.y, fmaf(a.z, wv2.y, fmaf(a.w, wv3.y, acc[j][1]))));
                acc[j][2] = fmaf(a.x, wv0.z, fmaf(a.y, wv1.z, fmaf(a.z, wv2.z, fmaf(a.w, wv3.z, acc[j][2]))));
                acc[j][3] = fmaf(a.x, wv0.w, fmaf(a.y, wv1.w, fmaf(a.z, wv2.w, fmaf(a.w, wv3.w, acc[j][3]))));
            }
        }
    }

    // epilogue: per-column BN fold, relu, float4 stores
    float sc[4], sh[4];
#pragma unroll
    for (int q = 0; q < 4; ++q) {
        int c = c0 + q;
        sc[q] = gamma[c] * rsqrtf(var[c] + BN_EPS);
        sh[q] = (bias[c] - mean[c]) * sc[q] + beta[c];
    }
#pragma unroll
    for (int j = 0; j < 4; ++j) {
        int row = row0 + r0 + j;
        if (row < NN) {
            float4 o;
            o.x = fmaxf(fmaf(acc[j][0], sc[0], sh[0]), 0.f);
            o.y = fmaxf(fmaf(acc[j][1], sc[1], sh[1]), 0.f);
            o.z = fmaxf(fmaf(acc[j][2], sc[2], sh[2]), 0.f);
            o.w = fmaxf(fmaf(acc[j][3], sc[3], sh[3]), 0.f);
            *(float4*)&Out[(size_t)row * DD + c0] = o;
        }
    }
}

// ---------------- fused mean-pool + linear head: one block per graph ----------------
__launch_bounds__(256)
__global__ void pool_head(const float* __restrict__ x, const int* __restrict__ goff,
                          const float* __restrict__ inv, const float* __restrict__ fcw,
                          const float* __restrict__ fcb, float* __restrict__ out) {
    int g = blockIdx.x;
    int t = threadIdx.x;
    int start = goff[g], end = goff[g + 1];
    int d  = (t & 63) * 2;
    int rs = t >> 6;                   // 0..3
    float ax = 0.f, ay = 0.f;
    for (int n = start + rs; n < end; n += 4) {
        float2 v = *(const float2*)&x[(size_t)n * DD + d];
        ax += v.x; ay += v.y;
    }
    __shared__ float red[4][DD];
    red[rs][d] = ax; red[rs][d + 1] = ay;
    __syncthreads();
    __shared__ float pooled[DD];
    if (t < DD) pooled[t] = red[0][t] + red[1][t] + red[2][t] + red[3][t];
    __syncthreads();
    if (t < OO) {
        float s = 0.f;
        for (int dd = 0; dd < DD; ++dd)
            s = fmaf(pooled[dd], fcw[dd * OO + t], s);
        out[g * OO + t] += s * inv[g] + fcb[t];
    }
}

extern "C" void kernel_launch(void* const* d_in, const int* in_sizes, int n_in,
                              void* d_out, int out_size, void* d_ws, size_t ws_size,
                              hipStream_t stream) {
    const float* x_in    = (const float*)d_in[0];
    const int*   ei      = (const int*)d_in[1];
    const int*   eattr   = (const int*)d_in[2];
    const int*   batch   = (const int*)d_in[3];
    const float* bond    = (const float*)d_in[4];
    const float* conv_w1 = (const float*)d_in[5];
    const float* conv_b1 = (const float*)d_in[6];
    const float* cbg     = (const float*)d_in[7];
    const float* cbb     = (const float*)d_in[8];
    const float* cbm     = (const float*)d_in[9];
    const float* cbv     = (const float*)d_in[10];
    const float* conv_w2 = (const float*)d_in[11];
    const float* conv_b2 = (const float*)d_in[12];
    const float* bg      = (const float*)d_in[13];
    const float* bb      = (const float*)d_in[14];
    const float* bm      = (const float*)d_in[15];
    const float* bv      = (const float*)d_in[16];
    const float* fcw     = (const float*)d_in[17];
    const float* fcb     = (const float*)d_in[18];
    float* out = (float*)d_out;

    // workspace layout
    float*    ws     = (float*)d_ws;
    float*    cur    = ws;                                   // N*D
    float*    aggrh  = cur + (size_t)NN * DD;                // N*D (aggr, then aliased as h1)
    int*      off    = (int*)(aggrh + (size_t)NN * DD);      // N+1
    unsigned* e_info = (unsigned*)(off + NN + 1);            // E
    int*      goff   = (int*)(e_info + EE);                  // G+1
    float*    inv    = (float*)(goff + GG + 1);              // G
    int*      deg    = (int*)(inv + GG);                     // N
    int*      epos   = deg + NN;                             // N
    int*      gcnt   = epos + NN;                            // G

    hipMemsetAsync(deg, 0, NN * sizeof(int), stream);
    hipMemsetAsync(gcnt, 0, GG * sizeof(int), stream);
    hipMemsetAsync(out, 0, (size_t)GG * OO * sizeof(float), stream);

    // CSR build (edge topology is static across layers)
    deg_kernel<<<(EE + 255) / 256, 256, 0, stream>>>(ei, deg);
    gcount_kernel<<<(NN + 255) / 256, 256, 0, stream>>>(batch, gcnt);
    scan_off<<<1, 1024, 0, stream>>>(deg, off, epos);
    gscan<<<1, 256, 0, stream>>>(gcnt, goff, inv);
    scatter_edges<<<(EE + 255) / 256, 256, 0, stream>>>(ei, eattr, epos, e_info);

    // layer-0 head on raw input x
    pool_head<<<GG, 256, 0, stream>>>(x_in, goff, inv, fcw, fcb, out);

    const int gemm_blocks = (NN + 31) / 32;
    const int aggr_blocks = (NN + 3) / 4;
    const float* xcur = x_in;
    for (int i = 0; i < LL; ++i) {
        aggr_csr<<<aggr_blocks, 256, 0, stream>>>(
            xcur, off, e_info, bond + (size_t)i * 3 * 8 * DD, aggrh);
        // gemm1: reads xcur + aggrh, writes h1 (aliases aggrh: each block writes only
        // the same 32 rows it staged, after staging -> no cross-block hazard)
        gemm_bn_relu<<<gemm_blocks, 256, 0, stream>>>(
            xcur, aggrh,
            conv_w1 + (size_t)i * DD * DD, conv_b1 + (size_t)i * DD,
            cbg + (size_t)i * DD, cbb + (size_t)i * DD,
            cbm + (size_t)i * DD, cbv + (size_t)i * DD, aggrh);
        gemm_bn_relu<<<gemm_blocks, 256, 0, stream>>>(
            aggrh, nullptr,
            conv_w2 + (size_t)i * DD * DD, conv_b2 + (size_t)i * DD,
            bg + (size_t)i * DD, bb + (size_t)i * DD,
            bm + (size_t)i * DD, bv + (size_t)i * DD, cur);
        pool_head<<<GG, 256, 0, stream>>>(
            cur, goff, inv, fcw + (size_t)(i + 1) * DD * OO, fcb + (size_t)(i + 1) * OO, out);
        xcur = cur;
    }
}

// Round 3
// 740.050 us; speedup vs baseline: 9.1765x; 1.6557x over previous
//
#include <hip/hip_runtime.h>

#define NN 50000
#define EE 600000
#define DD 128
#define GG 256
#define LL 5
#define OO 10
#define BN_EPS 1e-5f

typedef __attribute__((ext_vector_type(8))) short short8;
typedef __attribute__((ext_vector_type(16))) float float16;

__device__ __forceinline__ unsigned short f2b(float f) {   // fp32 -> bf16 RNE
    unsigned u = __float_as_uint(f);
    unsigned r = u + 0x7FFFu + ((u >> 16) & 1u);
    return (unsigned short)(r >> 16);
}
__device__ __forceinline__ float blo(unsigned u) { return __uint_as_float(u << 16); }
__device__ __forceinline__ float bhi(unsigned u) { return __uint_as_float(u & 0xFFFF0000u); }

// ---------------- prep: x_in -> bf16 ----------------
__launch_bounds__(256)
__global__ void cvt_x(const float* __restrict__ x, unsigned* __restrict__ xb) {
    int i = blockIdx.x * 256 + threadIdx.x;          // one uint = 2 bf16
    if (i >= NN * DD / 2) return;
    float2 v = *(const float2*)&x[(size_t)i * 2];
    xb[i] = (unsigned)f2b(v.x) | ((unsigned)f2b(v.y) << 16);
}

// ---------------- prep: bond combo table combo[l][a2a1a0][d] ----------------
__launch_bounds__(128)
__global__ void build_combo(const float* __restrict__ bond, float* __restrict__ combo) {
    int l = blockIdx.x >> 9, c = blockIdx.x & 511, d = threadIdx.x;
    const float* b = bond + (size_t)l * 3 * 8 * DD;
    combo[((size_t)l * 512 + c) * DD + d] =
        b[(c & 7) * DD + d] + b[(8 + ((c >> 3) & 7)) * DD + d] + b[(16 + (c >> 6)) * DD + d];
}

// ---------------- prep: W -> bf16 transposed Wt[c][k] ----------------
__launch_bounds__(256)
__global__ void prep_wt(const float* __restrict__ w1, const float* __restrict__ w2,
                        short* __restrict__ wt) {
    int idx = blockIdx.x * 256 + threadIdx.x;        // 10 * 16384
    if (idx >= 10 * DD * DD) return;
    int mat = idx >> 14, e = idx & 16383;
    int c = e >> 7, k = e & 127;
    const float* W = (mat < 5) ? (w1 + (size_t)mat * DD * DD)
                               : (w2 + (size_t)(mat - 5) * DD * DD);
    wt[idx] = (short)f2b(W[k * DD + c]);
}

// ---------------- CSR build ----------------
__launch_bounds__(256)
__global__ void deg_kernel(const int* __restrict__ ei, int* __restrict__ deg) {
    int e = blockIdx.x * 256 + threadIdx.x;
    if (e < EE) atomicAdd(&deg[ei[EE + e]], 1);
}

__launch_bounds__(256)
__global__ void gcount_kernel(const int* __restrict__ batch, int* __restrict__ gcnt) {
    int n = blockIdx.x * 256 + threadIdx.x;
    if (n < NN) atomicAdd(&gcnt[batch[n]], 1);
}

__launch_bounds__(256)
__global__ void bsum_kernel(const int* __restrict__ deg, int* __restrict__ bsum) {
    __shared__ int sh[256];
    int n = blockIdx.x * 256 + threadIdx.x;
    sh[threadIdx.x] = (n < NN) ? deg[n] : 0;
    __syncthreads();
    for (int d = 128; d > 0; d >>= 1) {
        if (threadIdx.x < d) sh[threadIdx.x] += sh[threadIdx.x + d];
        __syncthreads();
    }
    if (threadIdx.x == 0) bsum[blockIdx.x] = sh[0];
}

__launch_bounds__(256)
__global__ void scan_bsum(const int* __restrict__ bsum, int* __restrict__ bpref, int nb) {
    __shared__ int sh[256];
    int t = threadIdx.x;
    int v = (t < nb) ? bsum[t] : 0;
    sh[t] = v;
    __syncthreads();
    for (int d = 1; d < 256; d <<= 1) {
        int u = (t >= d) ? sh[t - d] : 0;
        __syncthreads();
        sh[t] += u;
        __syncthreads();
    }
    if (t < nb) bpref[t] = sh[t] - v;   // exclusive
}

__launch_bounds__(256)
__global__ void emit_off(const int* __restrict__ deg, const int* __restrict__ bpref,
                         int* __restrict__ off, int* __restrict__ epos) {
    __shared__ int sh[256];
    int t = threadIdx.x, n = blockIdx.x * 256 + t;
    int d = (n < NN) ? deg[n] : 0;
    sh[t] = d;
    __syncthreads();
    for (int s = 1; s < 256; s <<= 1) {
        int u = (t >= s) ? sh[t - s] : 0;
        __syncthreads();
        sh[t] += u;
        __syncthreads();
    }
    int ex = bpref[blockIdx.x] + sh[t] - d;
    if (n < NN) { off[n] = ex; epos[n] = ex; }
    else if (n == NN) off[n] = ex;
}

__launch_bounds__(256)
__global__ void gscan(const int* __restrict__ gcnt, int* __restrict__ goff,
                      float* __restrict__ inv) {
    __shared__ int part[GG];
    int t = threadIdx.x;
    int c = gcnt[t];
    part[t] = c;
    __syncthreads();
    for (int d = 1; d < GG; d <<= 1) {
        int v = (t >= d) ? part[t - d] : 0;
        __syncthreads();
        part[t] += v;
        __syncthreads();
    }
    goff[t] = part[t] - c;
    if (t == GG - 1) goff[GG] = part[GG - 1];
    inv[t] = 1.0f / fmaxf((float)c, 1.0f);
}

// payload: src (16b) | combo index (9b) << 16
__launch_bounds__(256)
__global__ void scatter_edges(const int* __restrict__ ei, const int* __restrict__ eattr,
                              int* __restrict__ epos, unsigned* __restrict__ e_info) {
    int e = blockIdx.x * 256 + threadIdx.x;
    if (e >= EE) return;
    int dst = ei[EE + e];
    int pos = atomicAdd(&epos[dst], 1);
    unsigned cidx = (unsigned)eattr[e * 3 + 0] | ((unsigned)eattr[e * 3 + 1] << 3)
                  | ((unsigned)eattr[e * 3 + 2] << 6);
    e_info[pos] = (unsigned)ei[e] | (cidx << 16);
}

// ---------------- CSR aggregation: one wave per node, bf16 x, combo table ----------------
__launch_bounds__(256)
__global__ void aggr_csr(const unsigned short* __restrict__ xb, const int* __restrict__ off,
                         const unsigned* __restrict__ e_info, const float* __restrict__ combo,
                         float* __restrict__ aggr) {
    int node = blockIdx.x * 4 + (threadIdx.x >> 6);
    int lane = threadIdx.x & 63;
    if (node >= NN) return;
    int p = off[node], pe = off[node + 1];
    int d = lane * 2;
    float ax = 0.f, ay = 0.f;
    for (; p + 1 < pe; p += 2) {
        unsigned i0 = e_info[p], i1 = e_info[p + 1];
        unsigned x0 = *(const unsigned*)&xb[(i0 & 0xFFFFu) * DD + d];
        float2  c0 = *(const float2*)&combo[(size_t)(i0 >> 16) * DD + d];
        unsigned x1 = *(const unsigned*)&xb[(i1 & 0xFFFFu) * DD + d];
        float2  c1 = *(const float2*)&combo[(size_t)(i1 >> 16) * DD + d];
        ax += fmaxf(blo(x0) + c0.x, 0.f) + fmaxf(blo(x1) + c1.x, 0.f);
        ay += fmaxf(bhi(x0) + c0.y, 0.f) + fmaxf(bhi(x1) + c1.y, 0.f);
    }
    if (p < pe) {
        unsigned i0 = e_info[p];
        unsigned x0 = *(const unsigned*)&xb[(i0 & 0xFFFFu) * DD + d];
        float2  c0 = *(const float2*)&combo[(size_t)(i0 >> 16) * DD + d];
        ax += fmaxf(blo(x0) + c0.x, 0.f);
        ay += fmaxf(bhi(x0) + c0.y, 0.f);
    }
    float2 r; r.x = ax; r.y = ay;
    *(float2*)&aggr[(size_t)node * DD + d] = r;
}

// ---------------- MFMA GEMM + bias + BN + ReLU ----------------
// 64 rows/block, 4 waves; wave w owns cols [32w, 32w+32). B frags in VGPRs from Wt.
// Out fp32; optional bf16 shadow copy Outb.
__launch_bounds__(256)
__global__ void gemm_mfma(const float* __restrict__ A, const float* __restrict__ Add,
                          const short* __restrict__ Wt,    // [c][k] bf16
                          const float* __restrict__ bias, const float* __restrict__ gamma,
                          const float* __restrict__ beta, const float* __restrict__ mean,
                          const float* __restrict__ var,
                          float* __restrict__ Out, unsigned short* __restrict__ Outb) {
    __shared__ short As[64 * 136];                 // bf16, stride 136 (+8 pad)
    const int tid  = threadIdx.x;
    const int lane = tid & 63;
    const int wave = tid >> 6;
    const int row0 = blockIdx.x * 64;

    const int col   = wave * 32 + (lane & 31);
    const int khalf = (lane >> 5) * 8;

    // B fragments: lane holds B[k=ch*16+khalf+j][col], j=0..7 (contiguous in Wt[c][k])
    short8 b[8];
#pragma unroll
    for (int ch = 0; ch < 8; ++ch)
        b[ch] = *(const short8*)&Wt[col * DD + ch * 16 + khalf];

    const float scale = gamma[col] * rsqrtf(var[col] + BN_EPS);
    const float shift = fmaf(bias[col] - mean[col], scale, beta[col]);

    // stage A tile fp32 -> bf16 (RNE), optionally + Add
    for (int i = tid; i < 64 * 32; i += 256) {
        int r = i >> 5, c4 = (i & 31) * 4;
        int row = row0 + r;
        float4 v = make_float4(0.f, 0.f, 0.f, 0.f);
        if (row < NN) {
            v = *(const float4*)&A[(size_t)row * DD + c4];
            if (Add) {
                float4 w = *(const float4*)&Add[(size_t)row * DD + c4];
                v.x += w.x; v.y += w.y; v.z += w.z; v.w += w.w;
            }
        }
        unsigned u0 = (unsigned)f2b(v.x) | ((unsigned)f2b(v.y) << 16);
        unsigned u1 = (unsigned)f2b(v.z) | ((unsigned)f2b(v.w) << 16);
        uint2 pk; pk.x = u0; pk.y = u1;
        *(uint2*)&As[r * 136 + c4] = pk;
    }
    __syncthreads();

    const int arow = lane & 31;
#pragma unroll
    for (int s = 0; s < 2; ++s) {
        float16 acc = {0.f,0.f,0.f,0.f,0.f,0.f,0.f,0.f,0.f,0.f,0.f,0.f,0.f,0.f,0.f,0.f};
#pragma unroll
        for (int ch = 0; ch < 8; ++ch) {
            short8 a = *(const short8*)&As[(s * 32 + arow) * 136 + ch * 16 + khalf];
            acc = __builtin_amdgcn_mfma_f32_32x32x16_bf16(a, b[ch], acc, 0, 0, 0);
        }
        // C/D: col = lane&31 (within wave tile), row = (reg&3) + 8*(reg>>2) + 4*(lane>>5)
#pragma unroll
        for (int r = 0; r < 16; ++r) {
            int row = row0 + s * 32 + (r & 3) + 8 * (r >> 2) + 4 * (lane >> 5);
            if (row < NN) {
                float v = fmaxf(fmaf(acc[r], scale, shift), 0.f);
                Out[(size_t)row * DD + col] = v;
                if (Outb) Outb[(size_t)row * DD + col] = f2b(v);
            }
        }
    }
}

// ---------------- fused mean-pool + linear head ----------------
__launch_bounds__(256)
__global__ void pool_head(const float* __restrict__ x, const int* __restrict__ goff,
                          const float* __restrict__ inv, const float* __restrict__ fcw,
                          const float* __restrict__ fcb, float* __restrict__ out) {
    int g = blockIdx.x;
    int t = threadIdx.x;
    int start = goff[g], end = goff[g + 1];
    int d  = (t & 63) * 2;
    int rs = t >> 6;
    float ax = 0.f, ay = 0.f;
    for (int n = start + rs; n < end; n += 4) {
        float2 v = *(const float2*)&x[(size_t)n * DD + d];
        ax += v.x; ay += v.y;
    }
    __shared__ float red[4][DD];
    red[rs][d] = ax; red[rs][d + 1] = ay;
    __syncthreads();
    __shared__ float pooled[DD];
    if (t < DD) pooled[t] = red[0][t] + red[1][t] + red[2][t] + red[3][t];
    __syncthreads();
    if (t < OO) {
        float s = 0.f;
        for (int dd = 0; dd < DD; ++dd)
            s = fmaf(pooled[dd], fcw[dd * OO + t], s);
        out[g * OO + t] += s * inv[g] + fcb[t];
    }
}

extern "C" void kernel_launch(void* const* d_in, const int* in_sizes, int n_in,
                              void* d_out, int out_size, void* d_ws, size_t ws_size,
                              hipStream_t stream) {
    const float* x_in    = (const float*)d_in[0];
    const int*   ei      = (const int*)d_in[1];
    const int*   eattr   = (const int*)d_in[2];
    const int*   batch   = (const int*)d_in[3];
    const float* bond    = (const float*)d_in[4];
    const float* conv_w1 = (const float*)d_in[5];
    const float* conv_b1 = (const float*)d_in[6];
    const float* cbg     = (const float*)d_in[7];
    const float* cbb     = (const float*)d_in[8];
    const float* cbm     = (const float*)d_in[9];
    const float* cbv     = (const float*)d_in[10];
    const float* conv_w2 = (const float*)d_in[11];
    const float* conv_b2 = (const float*)d_in[12];
    const float* bg      = (const float*)d_in[13];
    const float* bb      = (const float*)d_in[14];
    const float* bm      = (const float*)d_in[15];
    const float* bv      = (const float*)d_in[16];
    const float* fcw     = (const float*)d_in[17];
    const float* fcb     = (const float*)d_in[18];
    float* out = (float*)d_out;

    // ---- workspace carve-up (16B-aligned chunks) ----
    char* base = (char*)d_ws;
    size_t o = 0;
    auto carve = [&](size_t bytes) { void* p = base + o; o += (bytes + 15) & ~(size_t)15; return p; };
    float*          cur    = (float*)carve((size_t)NN * DD * 4);
    float*          aggrh  = (float*)carve((size_t)NN * DD * 4);
    float*          combo  = (float*)carve((size_t)LL * 512 * DD * 4);
    float*          inv    = (float*)carve(GG * 4);
    unsigned short* curb   = (unsigned short*)carve((size_t)NN * DD * 2);
    short*          wt     = (short*)carve((size_t)10 * DD * DD * 2);
    int*            off    = (int*)carve((NN + 1) * 4);
    int*            epos   = (int*)carve(NN * 4);
    int*            deg    = (int*)carve(NN * 4);
    unsigned*       e_info = (unsigned*)carve((size_t)EE * 4);
    int*            goff   = (int*)carve((GG + 1) * 4);
    int*            gcnt   = (int*)carve(GG * 4);
    int*            bsum   = (int*)carve(256 * 4);
    int*            bpref  = (int*)carve(256 * 4);

    hipMemsetAsync(deg, 0, NN * sizeof(int), stream);
    hipMemsetAsync(gcnt, 0, GG * sizeof(int), stream);
    hipMemsetAsync(out, 0, (size_t)GG * OO * sizeof(float), stream);

    const int NB = (NN + 255) / 256;   // 196

    // prep (independent of CSR build)
    cvt_x<<<(NN * DD / 2 + 255) / 256, 256, 0, stream>>>(x_in, (unsigned*)curb);
    build_combo<<<LL * 512, 128, 0, stream>>>(bond, combo);
    prep_wt<<<(10 * DD * DD + 255) / 256, 256, 0, stream>>>(conv_w1, conv_w2, wt);

    // CSR build
    deg_kernel<<<(EE + 255) / 256, 256, 0, stream>>>(ei, deg);
    gcount_kernel<<<NB, 256, 0, stream>>>(batch, gcnt);
    bsum_kernel<<<NB, 256, 0, stream>>>(deg, bsum);
    scan_bsum<<<1, 256, 0, stream>>>(bsum, bpref, NB);
    emit_off<<<NB, 256, 0, stream>>>(deg, bpref, off, epos);
    gscan<<<1, 256, 0, stream>>>(gcnt, goff, inv);
    scatter_edges<<<(EE + 255) / 256, 256, 0, stream>>>(ei, eattr, epos, e_info);

    // layer-0 head on raw input x
    pool_head<<<GG, 256, 0, stream>>>(x_in, goff, inv, fcw, fcb, out);

    const int gemm_blocks = (NN + 63) / 64;     // 782
    const int aggr_blocks = (NN + 3) / 4;
    const float* xcur = x_in;
    for (int i = 0; i < LL; ++i) {
        aggr_csr<<<aggr_blocks, 256, 0, stream>>>(
            curb, off, e_info, combo + (size_t)i * 512 * DD, aggrh);
        // gemm1: reads xcur+aggrh (own rows only, before sync), writes h1 (aliases aggrh)
        gemm_mfma<<<gemm_blocks, 256, 0, stream>>>(
            xcur, aggrh, wt + (size_t)i * DD * DD,
            conv_b1 + (size_t)i * DD, cbg + (size_t)i * DD, cbb + (size_t)i * DD,
            cbm + (size_t)i * DD, cbv + (size_t)i * DD, aggrh, nullptr);
        // gemm2: writes fp32 cur + bf16 curb (consumed by next layer's aggr)
        gemm_mfma<<<gemm_blocks, 256, 0, stream>>>(
            aggrh, nullptr, wt + (size_t)(5 + i) * DD * DD,
            conv_b2 + (size_t)i * DD, bg + (size_t)i * DD, bb + (size_t)i * DD,
            bm + (size_t)i * DD, bv + (size_t)i * DD, cur, curb);
        pool_head<<<GG, 256, 0, stream>>>(
            cur, goff, inv, fcw + (size_t)(i + 1) * DD * OO, fcb + (size_t)(i + 1) * OO, out);
        xcur = cur;
    }
}

// Round 4
// 575.106 us; speedup vs baseline: 11.8084x; 1.2868x over previous
//
#include <hip/hip_runtime.h>

#define NN 50000
#define EE 600000
#define DD 128
#define GG 256
#define LL 5
#define OO 10
#define BN_EPS 1e-5f

typedef __attribute__((ext_vector_type(8))) short short8;
typedef __attribute__((ext_vector_type(16))) float float16;

__device__ __forceinline__ unsigned short f2b(float f) {   // fp32 -> bf16 RNE
    unsigned u = __float_as_uint(f);
    unsigned r = u + 0x7FFFu + ((u >> 16) & 1u);
    return (unsigned short)(r >> 16);
}
__device__ __forceinline__ float blo(unsigned u) { return __uint_as_float(u << 16); }
__device__ __forceinline__ float bhi(unsigned u) { return __uint_as_float(u & 0xFFFF0000u); }

// ---------------- prep: x_in -> bf16 ----------------
__launch_bounds__(256)
__global__ void cvt_x(const float* __restrict__ x, unsigned* __restrict__ xb) {
    int i = blockIdx.x * 256 + threadIdx.x;          // one uint = 2 bf16
    if (i >= NN * DD / 2) return;
    float2 v = *(const float2*)&x[(size_t)i * 2];
    xb[i] = (unsigned)f2b(v.x) | ((unsigned)f2b(v.y) << 16);
}

// ---------------- prep: bond combo table (bf16) combo[l][a2a1a0][d] ----------------
__launch_bounds__(128)
__global__ void build_combo(const float* __restrict__ bond, unsigned short* __restrict__ combo) {
    int l = blockIdx.x >> 9, c = blockIdx.x & 511, d = threadIdx.x;
    const float* b = bond + (size_t)l * 3 * 8 * DD;
    float s = b[(c & 7) * DD + d] + b[(8 + ((c >> 3) & 7)) * DD + d] + b[(16 + (c >> 6)) * DD + d];
    combo[((size_t)l * 512 + c) * DD + d] = f2b(s);
}

// ---------------- prep: W -> bf16 transposed Wt[c][k] ----------------
__launch_bounds__(256)
__global__ void prep_wt(const float* __restrict__ w1, const float* __restrict__ w2,
                        short* __restrict__ wt) {
    int idx = blockIdx.x * 256 + threadIdx.x;        // 10 * 16384
    if (idx >= 10 * DD * DD) return;
    int mat = idx >> 14, e = idx & 16383;
    int c = e >> 7, k = e & 127;
    const float* W = (mat < 5) ? (w1 + (size_t)mat * DD * DD)
                               : (w2 + (size_t)(mat - 5) * DD * DD);
    wt[idx] = (short)f2b(W[k * DD + c]);
}

// ---------------- CSR build ----------------
__launch_bounds__(256)
__global__ void deg_kernel(const int* __restrict__ ei, int* __restrict__ deg) {
    int e = blockIdx.x * 256 + threadIdx.x;
    if (e < EE) atomicAdd(&deg[ei[EE + e]], 1);
}

__launch_bounds__(256)
__global__ void bsum_kernel(const int* __restrict__ deg, int* __restrict__ bsum) {
    __shared__ int sh[256];
    int n = blockIdx.x * 256 + threadIdx.x;
    sh[threadIdx.x] = (n < NN) ? deg[n] : 0;
    __syncthreads();
    for (int d = 128; d > 0; d >>= 1) {
        if (threadIdx.x < d) sh[threadIdx.x] += sh[threadIdx.x + d];
        __syncthreads();
    }
    if (threadIdx.x == 0) bsum[blockIdx.x] = sh[0];
}

__launch_bounds__(256)
__global__ void scan_bsum(const int* __restrict__ bsum, int* __restrict__ bpref, int nb) {
    __shared__ int sh[256];
    int t = threadIdx.x;
    int v = (t < nb) ? bsum[t] : 0;
    sh[t] = v;
    __syncthreads();
    for (int d = 1; d < 256; d <<= 1) {
        int u = (t >= d) ? sh[t - d] : 0;
        __syncthreads();
        sh[t] += u;
        __syncthreads();
    }
    if (t < nb) bpref[t] = sh[t] - v;   // exclusive
}

__launch_bounds__(256)
__global__ void emit_off(const int* __restrict__ deg, const int* __restrict__ bpref,
                         int* __restrict__ off, int* __restrict__ epos) {
    __shared__ int sh[256];
    int t = threadIdx.x, n = blockIdx.x * 256 + t;
    int d = (n < NN) ? deg[n] : 0;
    sh[t] = d;
    __syncthreads();
    for (int s = 1; s < 256; s <<= 1) {
        int u = (t >= s) ? sh[t - s] : 0;
        __syncthreads();
        sh[t] += u;
        __syncthreads();
    }
    int ex = bpref[blockIdx.x] + sh[t] - d;
    if (n < NN) { off[n] = ex; epos[n] = ex; }
    else if (n == NN) off[n] = ex;
}

// ---------------- graph offsets via binary search on sorted batch ----------------
__launch_bounds__(256)
__global__ void goff_inv(const int* __restrict__ batch, int* __restrict__ goff,
                         float* __restrict__ inv) {
    __shared__ int sg[GG + 1];
    int g = threadIdx.x;
    int lo = 0, hi = NN;
    while (lo < hi) { int mid = (lo + hi) >> 1; if (batch[mid] < g) lo = mid + 1; else hi = mid; }
    sg[g] = lo;
    if (g == 0) sg[GG] = NN;
    __syncthreads();
    goff[g] = sg[g];
    if (g == 0) goff[GG] = NN;
    inv[g] = 1.0f / fmaxf((float)(sg[g + 1] - sg[g]), 1.0f);
}

// payload: src (16b) | combo index (9b) << 16
__launch_bounds__(256)
__global__ void scatter_edges(const int* __restrict__ ei, const int* __restrict__ eattr,
                              int* __restrict__ epos, unsigned* __restrict__ e_info) {
    int e = blockIdx.x * 256 + threadIdx.x;
    if (e >= EE) return;
    int dst = ei[EE + e];
    int pos = atomicAdd(&epos[dst], 1);
    unsigned cidx = (unsigned)eattr[e * 3 + 0] | ((unsigned)eattr[e * 3 + 1] << 3)
                  | ((unsigned)eattr[e * 3 + 2] << 6);
    e_info[pos] = (unsigned)ei[e] | (cidx << 16);
}

// ---------------- CSR aggregation + residual: hin = x + sum relu(x_src + combo), bf16 ----------------
__launch_bounds__(256)
__global__ void aggr_csr(const unsigned short* __restrict__ xb, const int* __restrict__ off,
                         const unsigned* __restrict__ e_info,
                         const unsigned short* __restrict__ combo,
                         unsigned short* __restrict__ hin) {
    int node = blockIdx.x * 4 + (threadIdx.x >> 6);
    int lane = threadIdx.x & 63;
    if (node >= NN) return;
    int p = off[node], pe = off[node + 1];
    int d = lane * 2;
    unsigned self = *(const unsigned*)&xb[(size_t)node * DD + d];
    float ax = blo(self), ay = bhi(self);
    for (; p + 1 < pe; p += 2) {
        unsigned i0 = e_info[p], i1 = e_info[p + 1];
        unsigned x0 = *(const unsigned*)&xb[(i0 & 0xFFFFu) * DD + d];
        unsigned c0 = *(const unsigned*)&combo[(size_t)(i0 >> 16) * DD + d];
        unsigned x1 = *(const unsigned*)&xb[(i1 & 0xFFFFu) * DD + d];
        unsigned c1 = *(const unsigned*)&combo[(size_t)(i1 >> 16) * DD + d];
        ax += fmaxf(blo(x0) + blo(c0), 0.f) + fmaxf(blo(x1) + blo(c1), 0.f);
        ay += fmaxf(bhi(x0) + bhi(c0), 0.f) + fmaxf(bhi(x1) + bhi(c1), 0.f);
    }
    if (p < pe) {
        unsigned i0 = e_info[p];
        unsigned x0 = *(const unsigned*)&xb[(i0 & 0xFFFFu) * DD + d];
        unsigned c0 = *(const unsigned*)&combo[(size_t)(i0 >> 16) * DD + d];
        ax += fmaxf(blo(x0) + blo(c0), 0.f);
        ay += fmaxf(bhi(x0) + bhi(c0), 0.f);
    }
    *(unsigned*)&hin[(size_t)node * DD + d] = (unsigned)f2b(ax) | ((unsigned)f2b(ay) << 16);
}

// ---------------- fused conv: relu(bn2(relu(bn1(hin@W1+b1))@W2+b2)) -> bf16 ----------------
// 64 rows/block, 4 waves; wave w owns cols [32w,32w+32). h1 round-trips through the
// A-tile LDS (aliased after a barrier).
__launch_bounds__(256)
__global__ void conv_fused(const unsigned short* __restrict__ hin,
                           const short* __restrict__ Wt1, const short* __restrict__ Wt2,
                           const float* __restrict__ b1, const float* __restrict__ g1,
                           const float* __restrict__ be1, const float* __restrict__ m1,
                           const float* __restrict__ v1,
                           const float* __restrict__ b2, const float* __restrict__ g2,
                           const float* __restrict__ be2, const float* __restrict__ m2,
                           const float* __restrict__ v2,
                           unsigned short* __restrict__ outb) {
    __shared__ short As[64 * 136];                 // bf16, stride 136 (272B = 17 x 16B)
    const int tid  = threadIdx.x;
    const int lane = tid & 63;
    const int wave = tid >> 6;
    const int row0 = blockIdx.x * 64;

    const int col   = wave * 32 + (lane & 31);
    const int khalf = (lane >> 5) * 8;
    const int arow  = lane & 31;
    const int rbase = 4 * (lane >> 5);

    short8 bf[8];
#pragma unroll
    for (int ch = 0; ch < 8; ++ch)
        bf[ch] = *(const short8*)&Wt1[col * DD + ch * 16 + khalf];

    const float sc1 = g1[col] * rsqrtf(v1[col] + BN_EPS);
    const float sh1 = fmaf(b1[col] - m1[col], sc1, be1[col]);
    const float sc2 = g2[col] * rsqrtf(v2[col] + BN_EPS);
    const float sh2 = fmaf(b2[col] - m2[col], sc2, be2[col]);

    // stage A tile: 64 rows x 128 bf16, uint4 (8 elems) per access
    for (int i = tid; i < 1024; i += 256) {
        int r = i >> 4, c8 = (i & 15) * 8;
        int row = row0 + r;
        uint4 z = make_uint4(0, 0, 0, 0);
        if (row < NN) z = *(const uint4*)&hin[(size_t)row * DD + c8];
        *(uint4*)&As[r * 136 + c8] = z;
    }
    __syncthreads();

    float16 acc0 = {0.f,0.f,0.f,0.f,0.f,0.f,0.f,0.f,0.f,0.f,0.f,0.f,0.f,0.f,0.f,0.f};
    float16 acc1 = acc0;
#pragma unroll
    for (int ch = 0; ch < 8; ++ch) {
        short8 a0 = *(const short8*)&As[(arow     ) * 136 + ch * 16 + khalf];
        short8 a1 = *(const short8*)&As[(32 + arow) * 136 + ch * 16 + khalf];
        acc0 = __builtin_amdgcn_mfma_f32_32x32x16_bf16(a0, bf[ch], acc0, 0, 0, 0);
        acc1 = __builtin_amdgcn_mfma_f32_32x32x16_bf16(a1, bf[ch], acc1, 0, 0, 0);
    }

    // B2 fragments (reuse bf regs)
#pragma unroll
    for (int ch = 0; ch < 8; ++ch)
        bf[ch] = *(const short8*)&Wt2[col * DD + ch * 16 + khalf];

    __syncthreads();   // all MFMA1 A-reads complete -> safe to overwrite As with h1
#pragma unroll
    for (int r = 0; r < 16; ++r) {
        int rl = (r & 3) + 8 * (r >> 2) + rbase;
        As[rl * 136 + col]        = (short)f2b(fmaxf(fmaf(acc0[r], sc1, sh1), 0.f));
        As[(32 + rl) * 136 + col] = (short)f2b(fmaxf(fmaf(acc1[r], sc1, sh1), 0.f));
    }
    __syncthreads();

    acc0 = acc1 = float16{0.f,0.f,0.f,0.f,0.f,0.f,0.f,0.f,0.f,0.f,0.f,0.f,0.f,0.f,0.f,0.f};
#pragma unroll
    for (int ch = 0; ch < 8; ++ch) {
        short8 a0 = *(const short8*)&As[(arow     ) * 136 + ch * 16 + khalf];
        short8 a1 = *(const short8*)&As[(32 + arow) * 136 + ch * 16 + khalf];
        acc0 = __builtin_amdgcn_mfma_f32_32x32x16_bf16(a0, bf[ch], acc0, 0, 0, 0);
        acc1 = __builtin_amdgcn_mfma_f32_32x32x16_bf16(a1, bf[ch], acc1, 0, 0, 0);
    }
#pragma unroll
    for (int r = 0; r < 16; ++r) {
        int rl = (r & 3) + 8 * (r >> 2) + rbase;
        int row = row0 + rl;
        if (row < NN)
            outb[(size_t)row * DD + col] = f2b(fmaxf(fmaf(acc0[r], sc2, sh2), 0.f));
        if (row + 32 < NN)
            outb[(size_t)(row + 32) * DD + col] = f2b(fmaxf(fmaf(acc1[r], sc2, sh2), 0.f));
    }
}

// ---------------- fused mean-pool + linear head (bf16 input) ----------------
__launch_bounds__(512)
__global__ void pool_head_bf(const unsigned short* __restrict__ x, const int* __restrict__ goff,
                             const float* __restrict__ inv, const float* __restrict__ fcw,
                             const float* __restrict__ fcb, float* __restrict__ out) {
    int g = blockIdx.x;
    int t = threadIdx.x;
    int start = goff[g], end = goff[g + 1];
    int d  = (t & 63) * 2;
    int rs = t >> 6;                   // 0..7
    float ax = 0.f, ay = 0.f;
    for (int n = start + rs; n < end; n += 8) {
        unsigned v = *(const unsigned*)&x[(size_t)n * DD + d];
        ax += blo(v); ay += bhi(v);
    }
    __shared__ float red[8][DD];
    red[rs][d] = ax; red[rs][d + 1] = ay;
    __syncthreads();
    __shared__ float pooled[DD];
    if (t < DD) {
        float s = 0.f;
#pragma unroll
        for (int j = 0; j < 8; ++j) s += red[j][t];
        pooled[t] = s;
    }
    __syncthreads();
    if (t < OO) {
        float s = 0.f;
        for (int dd = 0; dd < DD; ++dd)
            s = fmaf(pooled[dd], fcw[dd * OO + t], s);
        out[g * OO + t] += s * inv[g] + fcb[t];
    }
}

// ---------------- layer-0 pool+head on fp32 x_in ----------------
__launch_bounds__(512)
__global__ void pool_head_f32(const float* __restrict__ x, const int* __restrict__ goff,
                              const float* __restrict__ inv, const float* __restrict__ fcw,
                              const float* __restrict__ fcb, float* __restrict__ out) {
    int g = blockIdx.x;
    int t = threadIdx.x;
    int start = goff[g], end = goff[g + 1];
    int d  = (t & 63) * 2;
    int rs = t >> 6;
    float ax = 0.f, ay = 0.f;
    for (int n = start + rs; n < end; n += 8) {
        float2 v = *(const float2*)&x[(size_t)n * DD + d];
        ax += v.x; ay += v.y;
    }
    __shared__ float red[8][DD];
    red[rs][d] = ax; red[rs][d + 1] = ay;
    __syncthreads();
    __shared__ float pooled[DD];
    if (t < DD) {
        float s = 0.f;
#pragma unroll
        for (int j = 0; j < 8; ++j) s += red[j][t];
        pooled[t] = s;
    }
    __syncthreads();
    if (t < OO) {
        float s = 0.f;
        for (int dd = 0; dd < DD; ++dd)
            s = fmaf(pooled[dd], fcw[dd * OO + t], s);
        out[g * OO + t] += s * inv[g] + fcb[t];
    }
}

extern "C" void kernel_launch(void* const* d_in, const int* in_sizes, int n_in,
                              void* d_out, int out_size, void* d_ws, size_t ws_size,
                              hipStream_t stream) {
    const float* x_in    = (const float*)d_in[0];
    const int*   ei      = (const int*)d_in[1];
    const int*   eattr   = (const int*)d_in[2];
    const int*   batch   = (const int*)d_in[3];
    const float* bond    = (const float*)d_in[4];
    const float* conv_w1 = (const float*)d_in[5];
    const float* conv_b1 = (const float*)d_in[6];
    const float* cbg     = (const float*)d_in[7];
    const float* cbb     = (const float*)d_in[8];
    const float* cbm     = (const float*)d_in[9];
    const float* cbv     = (const float*)d_in[10];
    const float* conv_w2 = (const float*)d_in[11];
    const float* conv_b2 = (const float*)d_in[12];
    const float* bg      = (const float*)d_in[13];
    const float* bb      = (const float*)d_in[14];
    const float* bm      = (const float*)d_in[15];
    const float* bv      = (const float*)d_in[16];
    const float* fcw     = (const float*)d_in[17];
    const float* fcb     = (const float*)d_in[18];
    float* out = (float*)d_out;

    // ---- workspace carve-up (16B-aligned chunks) ----
    char* base = (char*)d_ws;
    size_t o = 0;
    auto carve = [&](size_t bytes) { void* p = base + o; o += (bytes + 15) & ~(size_t)15; return p; };
    unsigned short* xb     = (unsigned short*)carve((size_t)NN * DD * 2);
    unsigned short* hin    = (unsigned short*)carve((size_t)NN * DD * 2);
    unsigned short* combo  = (unsigned short*)carve((size_t)LL * 512 * DD * 2);
    short*          wt     = (short*)carve((size_t)10 * DD * DD * 2);
    float*          inv    = (float*)carve(GG * 4);
    int*            off    = (int*)carve((NN + 1) * 4);
    int*            epos   = (int*)carve(NN * 4);
    int*            deg    = (int*)carve(NN * 4);
    unsigned*       e_info = (unsigned*)carve((size_t)EE * 4);
    int*            goff   = (int*)carve((GG + 1) * 4);
    int*            bsum   = (int*)carve(256 * 4);
    int*            bpref  = (int*)carve(256 * 4);

    hipMemsetAsync(deg, 0, NN * sizeof(int), stream);
    hipMemsetAsync(out, 0, (size_t)GG * OO * sizeof(float), stream);

    const int NB = (NN + 255) / 256;   // 196

    // prep (independent of CSR build)
    cvt_x<<<(NN * DD / 2 + 255) / 256, 256, 0, stream>>>(x_in, (unsigned*)xb);
    build_combo<<<LL * 512, 128, 0, stream>>>(bond, combo);
    prep_wt<<<(10 * DD * DD + 255) / 256, 256, 0, stream>>>(conv_w1, conv_w2, wt);

    // CSR build
    deg_kernel<<<(EE + 255) / 256, 256, 0, stream>>>(ei, deg);
    bsum_kernel<<<NB, 256, 0, stream>>>(deg, bsum);
    scan_bsum<<<1, 256, 0, stream>>>(bsum, bpref, NB);
    emit_off<<<NB, 256, 0, stream>>>(deg, bpref, off, epos);
    goff_inv<<<1, 256, 0, stream>>>(batch, goff, inv);
    scatter_edges<<<(EE + 255) / 256, 256, 0, stream>>>(ei, eattr, epos, e_info);

    // layer-0 head on raw input x (fp32, unrounded)
    pool_head_f32<<<GG, 512, 0, stream>>>(x_in, goff, inv, fcw, fcb, out);

    const int conv_blocks = (NN + 63) / 64;     // 782
    const int aggr_blocks = (NN + 3) / 4;
    for (int i = 0; i < LL; ++i) {
        aggr_csr<<<aggr_blocks, 256, 0, stream>>>(
            xb, off, e_info, combo + (size_t)i * 512 * DD, hin);
        conv_fused<<<conv_blocks, 256, 0, stream>>>(
            hin, wt + (size_t)i * DD * DD, wt + (size_t)(5 + i) * DD * DD,
            conv_b1 + (size_t)i * DD, cbg + (size_t)i * DD, cbb + (size_t)i * DD,
            cbm + (size_t)i * DD, cbv + (size_t)i * DD,
            conv_b2 + (size_t)i * DD, bg + (size_t)i * DD, bb + (size_t)i * DD,
            bm + (size_t)i * DD, bv + (size_t)i * DD, xb);
        pool_head_bf<<<GG, 512, 0, stream>>>(
            xb, goff, inv, fcw + (size_t)(i + 1) * DD * OO, fcb + (size_t)(i + 1) * OO, out);
    }
}

// Round 5
// 498.469 us; speedup vs baseline: 13.6239x; 1.1537x over previous
//
#include <hip/hip_runtime.h>

#define NN 50000
#define EE 600000
#define DD 128
#define GG 256
#define LL 5
#define OO 10
#define BN_EPS 1e-5f
#define CPAD 513   // 512 combos + 1 sentinel (-1e30) row per layer

typedef __attribute__((ext_vector_type(8))) short short8;
typedef __attribute__((ext_vector_type(16))) float float16;

__device__ __forceinline__ unsigned short f2b(float f) {   // fp32 -> bf16 RNE
    unsigned u = __float_as_uint(f);
    unsigned r = u + 0x7FFFu + ((u >> 16) & 1u);
    return (unsigned short)(r >> 16);
}
__device__ __forceinline__ float blo(unsigned u) { return __uint_as_float(u << 16); }
__device__ __forceinline__ float bhi(unsigned u) { return __uint_as_float(u & 0xFFFF0000u); }

// ---------------- prep: x_in -> bf16 ----------------
__launch_bounds__(256)
__global__ void cvt_x(const float* __restrict__ x, unsigned* __restrict__ xb) {
    int i = blockIdx.x * 256 + threadIdx.x;          // one uint = 2 bf16
    if (i >= NN * DD / 2) return;
    float2 v = *(const float2*)&x[(size_t)i * 2];
    xb[i] = (unsigned)f2b(v.x) | ((unsigned)f2b(v.y) << 16);
}

// ---------------- prep: bond combo table (bf16) combo[l][cidx][d]; row 512 = -1e30 ----------------
__launch_bounds__(128)
__global__ void build_combo(const float* __restrict__ bond, unsigned short* __restrict__ combo) {
    int l = blockIdx.x / CPAD, c = blockIdx.x % CPAD, d = threadIdx.x;
    float s;
    if (c == 512) {
        s = -1e30f;                                  // sentinel: relu(x + s) == 0
    } else {
        const float* b = bond + (size_t)l * 3 * 8 * DD;
        s = b[(c & 7) * DD + d] + b[(8 + ((c >> 3) & 7)) * DD + d] + b[(16 + (c >> 6)) * DD + d];
    }
    combo[((size_t)l * CPAD + c) * DD + d] = f2b(s);
}

// ---------------- prep: W -> bf16 transposed Wt[c][k] ----------------
__launch_bounds__(256)
__global__ void prep_wt(const float* __restrict__ w1, const float* __restrict__ w2,
                        short* __restrict__ wt) {
    int idx = blockIdx.x * 256 + threadIdx.x;        // 10 * 16384
    if (idx >= 10 * DD * DD) return;
    int mat = idx >> 14, e = idx & 16383;
    int c = e >> 7, k = e & 127;
    const float* W = (mat < 5) ? (w1 + (size_t)mat * DD * DD)
                               : (w2 + (size_t)(mat - 5) * DD * DD);
    wt[idx] = (short)f2b(W[k * DD + c]);
}

// ---------------- CSR build (offsets padded to multiple of 8 edges/node) ----------------
__launch_bounds__(256)
__global__ void deg_kernel(const int* __restrict__ ei, int* __restrict__ deg) {
    int e = blockIdx.x * 256 + threadIdx.x;
    if (e < EE) atomicAdd(&deg[ei[EE + e]], 1);
}

__launch_bounds__(256)
__global__ void bsum_kernel(const int* __restrict__ deg, int* __restrict__ bsum) {
    __shared__ int sh[256];
    int n = blockIdx.x * 256 + threadIdx.x;
    sh[threadIdx.x] = (n < NN) ? ((deg[n] + 7) & ~7) : 0;
    __syncthreads();
    for (int d = 128; d > 0; d >>= 1) {
        if (threadIdx.x < d) sh[threadIdx.x] += sh[threadIdx.x + d];
        __syncthreads();
    }
    if (threadIdx.x == 0) bsum[blockIdx.x] = sh[0];
}

__launch_bounds__(256)
__global__ void scan_bsum(const int* __restrict__ bsum, int* __restrict__ bpref, int nb) {
    __shared__ int sh[256];
    int t = threadIdx.x;
    int v = (t < nb) ? bsum[t] : 0;
    sh[t] = v;
    __syncthreads();
    for (int d = 1; d < 256; d <<= 1) {
        int u = (t >= d) ? sh[t - d] : 0;
        __syncthreads();
        sh[t] += u;
        __syncthreads();
    }
    if (t < nb) bpref[t] = sh[t] - v;   // exclusive
}

__launch_bounds__(256)
__global__ void emit_off(const int* __restrict__ deg, const int* __restrict__ bpref,
                         int* __restrict__ off, int* __restrict__ epos) {
    __shared__ int sh[256];
    int t = threadIdx.x, n = blockIdx.x * 256 + t;
    int d = (n < NN) ? ((deg[n] + 7) & ~7) : 0;
    sh[t] = d;
    __syncthreads();
    for (int s = 1; s < 256; s <<= 1) {
        int u = (t >= s) ? sh[t - s] : 0;
        __syncthreads();
        sh[t] += u;
        __syncthreads();
    }
    int ex = bpref[blockIdx.x] + sh[t] - d;
    if (n < NN) { off[n] = ex; epos[n] = ex; }
    else if (n == NN) off[n] = ex;
}

// fill pad slots with sentinel edges (src 0, cidx 512)
__launch_bounds__(256)
__global__ void pad_fill(const int* __restrict__ off, const int* __restrict__ deg,
                         unsigned* __restrict__ e_info) {
    int n = blockIdx.x * 256 + threadIdx.x;
    if (n >= NN) return;
    int s = off[n] + deg[n], e = off[n + 1];
    for (int i = s; i < e; ++i) e_info[i] = (512u << 16);
}

// ---------------- graph offsets via binary search on sorted batch ----------------
__launch_bounds__(256)
__global__ void goff_inv(const int* __restrict__ batch, int* __restrict__ goff,
                         float* __restrict__ inv) {
    __shared__ int sg[GG + 1];
    int g = threadIdx.x;
    int lo = 0, hi = NN;
    while (lo < hi) { int mid = (lo + hi) >> 1; if (batch[mid] < g) lo = mid + 1; else hi = mid; }
    sg[g] = lo;
    if (g == 0) sg[GG] = NN;
    __syncthreads();
    goff[g] = sg[g];
    if (g == 0) goff[GG] = NN;
    inv[g] = 1.0f / fmaxf((float)(sg[g + 1] - sg[g]), 1.0f);
}

// payload: src (16b) | combo index (10b) << 16
__launch_bounds__(256)
__global__ void scatter_edges(const int* __restrict__ ei, const int* __restrict__ eattr,
                              int* __restrict__ epos, unsigned* __restrict__ e_info) {
    int e = blockIdx.x * 256 + threadIdx.x;
    if (e >= EE) return;
    int dst = ei[EE + e];
    int pos = atomicAdd(&epos[dst], 1);
    unsigned cidx = (unsigned)eattr[e * 3 + 0] | ((unsigned)eattr[e * 3 + 1] << 3)
                  | ((unsigned)eattr[e * 3 + 2] << 6);
    e_info[pos] = (unsigned)ei[e] | (cidx << 16);
}

// ---------------- CSR aggregation + residual, 8-edge batched (lists padded to x8) ----------------
// hin = x + sum relu(x_src + combo), all bf16 in/out, fp32 accumulate.
__launch_bounds__(256)
__global__ void aggr_csr(const unsigned short* __restrict__ xb, const int* __restrict__ off,
                         const unsigned* __restrict__ e_info,
                         const unsigned short* __restrict__ combo,
                         unsigned short* __restrict__ hin) {
    int node = blockIdx.x * 4 + (threadIdx.x >> 6);
    int lane = threadIdx.x & 63;
    if (node >= NN) return;
    int p = off[node], pe = off[node + 1];
    int d = lane * 2;
    unsigned self = *(const unsigned*)&xb[(size_t)node * DD + d];
    float ax = blo(self), ay = bhi(self);
    for (; p < pe; p += 8) {
        unsigned infv[8], xr[8], cr[8];
#pragma unroll
        for (int j = 0; j < 8; ++j) infv[j] = e_info[p + j];   // wave-uniform, all in flight
#pragma unroll
        for (int j = 0; j < 8; ++j) {
            xr[j] = *(const unsigned*)&xb[(size_t)(infv[j] & 0xFFFFu) * DD + d];
            cr[j] = *(const unsigned*)&combo[(size_t)(infv[j] >> 16) * DD + d];
        }
#pragma unroll
        for (int j = 0; j < 8; ++j) {
            ax += fmaxf(blo(xr[j]) + blo(cr[j]), 0.f);
            ay += fmaxf(bhi(xr[j]) + bhi(cr[j]), 0.f);
        }
    }
    *(unsigned*)&hin[(size_t)node * DD + d] = (unsigned)f2b(ax) | ((unsigned)f2b(ay) << 16);
}

// ---------------- fused conv: relu(bn2(relu(bn1(hin@W1+b1))@W2+b2)) -> bf16 ----------------
__launch_bounds__(256)
__global__ void conv_fused(const unsigned short* __restrict__ hin,
                           const short* __restrict__ Wt1, const short* __restrict__ Wt2,
                           const float* __restrict__ b1, const float* __restrict__ g1,
                           const float* __restrict__ be1, const float* __restrict__ m1,
                           const float* __restrict__ v1,
                           const float* __restrict__ b2, const float* __restrict__ g2,
                           const float* __restrict__ be2, const float* __restrict__ m2,
                           const float* __restrict__ v2,
                           unsigned short* __restrict__ outb) {
    __shared__ short As[64 * 136];
    const int tid  = threadIdx.x;
    const int lane = tid & 63;
    const int wave = tid >> 6;
    const int row0 = blockIdx.x * 64;

    const int col   = wave * 32 + (lane & 31);
    const int khalf = (lane >> 5) * 8;
    const int arow  = lane & 31;
    const int rbase = 4 * (lane >> 5);

    short8 bf[8];
#pragma unroll
    for (int ch = 0; ch < 8; ++ch)
        bf[ch] = *(const short8*)&Wt1[col * DD + ch * 16 + khalf];

    const float sc1 = g1[col] * rsqrtf(v1[col] + BN_EPS);
    const float sh1 = fmaf(b1[col] - m1[col], sc1, be1[col]);
    const float sc2 = g2[col] * rsqrtf(v2[col] + BN_EPS);
    const float sh2 = fmaf(b2[col] - m2[col], sc2, be2[col]);

    for (int i = tid; i < 1024; i += 256) {
        int r = i >> 4, c8 = (i & 15) * 8;
        int row = row0 + r;
        uint4 z = make_uint4(0, 0, 0, 0);
        if (row < NN) z = *(const uint4*)&hin[(size_t)row * DD + c8];
        *(uint4*)&As[r * 136 + c8] = z;
    }
    __syncthreads();

    float16 acc0 = {0.f,0.f,0.f,0.f,0.f,0.f,0.f,0.f,0.f,0.f,0.f,0.f,0.f,0.f,0.f,0.f};
    float16 acc1 = acc0;
#pragma unroll
    for (int ch = 0; ch < 8; ++ch) {
        short8 a0 = *(const short8*)&As[(arow     ) * 136 + ch * 16 + khalf];
        short8 a1 = *(const short8*)&As[(32 + arow) * 136 + ch * 16 + khalf];
        acc0 = __builtin_amdgcn_mfma_f32_32x32x16_bf16(a0, bf[ch], acc0, 0, 0, 0);
        acc1 = __builtin_amdgcn_mfma_f32_32x32x16_bf16(a1, bf[ch], acc1, 0, 0, 0);
    }

#pragma unroll
    for (int ch = 0; ch < 8; ++ch)
        bf[ch] = *(const short8*)&Wt2[col * DD + ch * 16 + khalf];

    __syncthreads();
#pragma unroll
    for (int r = 0; r < 16; ++r) {
        int rl = (r & 3) + 8 * (r >> 2) + rbase;
        As[rl * 136 + col]        = (short)f2b(fmaxf(fmaf(acc0[r], sc1, sh1), 0.f));
        As[(32 + rl) * 136 + col] = (short)f2b(fmaxf(fmaf(acc1[r], sc1, sh1), 0.f));
    }
    __syncthreads();

    acc0 = acc1 = float16{0.f,0.f,0.f,0.f,0.f,0.f,0.f,0.f,0.f,0.f,0.f,0.f,0.f,0.f,0.f,0.f};
#pragma unroll
    for (int ch = 0; ch < 8; ++ch) {
        short8 a0 = *(const short8*)&As[(arow     ) * 136 + ch * 16 + khalf];
        short8 a1 = *(const short8*)&As[(32 + arow) * 136 + ch * 16 + khalf];
        acc0 = __builtin_amdgcn_mfma_f32_32x32x16_bf16(a0, bf[ch], acc0, 0, 0, 0);
        acc1 = __builtin_amdgcn_mfma_f32_32x32x16_bf16(a1, bf[ch], acc1, 0, 0, 0);
    }
#pragma unroll
    for (int r = 0; r < 16; ++r) {
        int rl = (r & 3) + 8 * (r >> 2) + rbase;
        int row = row0 + rl;
        if (row < NN)
            outb[(size_t)row * DD + col] = f2b(fmaxf(fmaf(acc0[r], sc2, sh2), 0.f));
        if (row + 32 < NN)
            outb[(size_t)(row + 32) * DD + col] = f2b(fmaxf(fmaf(acc1[r], sc2, sh2), 0.f));
    }
}

// ---------------- fused mean-pool + linear head (bf16 input) ----------------
__launch_bounds__(512)
__global__ void pool_head_bf(const unsigned short* __restrict__ x, const int* __restrict__ goff,
                             const float* __restrict__ inv, const float* __restrict__ fcw,
                             const float* __restrict__ fcb, float* __restrict__ out) {
    int g = blockIdx.x;
    int t = threadIdx.x;
    int start = goff[g], end = goff[g + 1];
    int d  = (t & 63) * 2;
    int rs = t >> 6;                   // 0..7
    float ax = 0.f, ay = 0.f;
    for (int n = start + rs; n < end; n += 8) {
        unsigned v = *(const unsigned*)&x[(size_t)n * DD + d];
        ax += blo(v); ay += bhi(v);
    }
    __shared__ float red[8][DD];
    red[rs][d] = ax; red[rs][d + 1] = ay;
    __syncthreads();
    __shared__ float pooled[DD];
    if (t < DD) {
        float s = 0.f;
#pragma unroll
        for (int j = 0; j < 8; ++j) s += red[j][t];
        pooled[t] = s;
    }
    __syncthreads();
    if (t < OO) {
        float s = 0.f;
        for (int dd = 0; dd < DD; ++dd)
            s = fmaf(pooled[dd], fcw[dd * OO + t], s);
        out[g * OO + t] += s * inv[g] + fcb[t];
    }
}

// ---------------- layer-0 pool+head on fp32 x_in ----------------
__launch_bounds__(512)
__global__ void pool_head_f32(const float* __restrict__ x, const int* __restrict__ goff,
                              const float* __restrict__ inv, const float* __restrict__ fcw,
                              const float* __restrict__ fcb, float* __restrict__ out) {
    int g = blockIdx.x;
    int t = threadIdx.x;
    int start = goff[g], end = goff[g + 1];
    int d  = (t & 63) * 2;
    int rs = t >> 6;
    float ax = 0.f, ay = 0.f;
    for (int n = start + rs; n < end; n += 8) {
        float2 v = *(const float2*)&x[(size_t)n * DD + d];
        ax += v.x; ay += v.y;
    }
    __shared__ float red[8][DD];
    red[rs][d] = ax; red[rs][d + 1] = ay;
    __syncthreads();
    __shared__ float pooled[DD];
    if (t < DD) {
        float s = 0.f;
#pragma unroll
        for (int j = 0; j < 8; ++j) s += red[j][t];
        pooled[t] = s;
    }
    __syncthreads();
    if (t < OO) {
        float s = 0.f;
        for (int dd = 0; dd < DD; ++dd)
            s = fmaf(pooled[dd], fcw[dd * OO + t], s);
        out[g * OO + t] += s * inv[g] + fcb[t];
    }
}

extern "C" void kernel_launch(void* const* d_in, const int* in_sizes, int n_in,
                              void* d_out, int out_size, void* d_ws, size_t ws_size,
                              hipStream_t stream) {
    const float* x_in    = (const float*)d_in[0];
    const int*   ei      = (const int*)d_in[1];
    const int*   eattr   = (const int*)d_in[2];
    const int*   batch   = (const int*)d_in[3];
    const float* bond    = (const float*)d_in[4];
    const float* conv_w1 = (const float*)d_in[5];
    const float* conv_b1 = (const float*)d_in[6];
    const float* cbg     = (const float*)d_in[7];
    const float* cbb     = (const float*)d_in[8];
    const float* cbm     = (const float*)d_in[9];
    const float* cbv     = (const float*)d_in[10];
    const float* conv_w2 = (const float*)d_in[11];
    const float* conv_b2 = (const float*)d_in[12];
    const float* bg      = (const float*)d_in[13];
    const float* bb      = (const float*)d_in[14];
    const float* bm      = (const float*)d_in[15];
    const float* bv      = (const float*)d_in[16];
    const float* fcw     = (const float*)d_in[17];
    const float* fcb     = (const float*)d_in[18];
    float* out = (float*)d_out;

    // ---- workspace carve-up (16B-aligned chunks) ----
    char* base = (char*)d_ws;
    size_t o = 0;
    auto carve = [&](size_t bytes) { void* p = base + o; o += (bytes + 15) & ~(size_t)15; return p; };
    unsigned short* xb     = (unsigned short*)carve((size_t)NN * DD * 2);
    unsigned short* hin    = (unsigned short*)carve((size_t)NN * DD * 2);
    unsigned short* combo  = (unsigned short*)carve((size_t)LL * CPAD * DD * 2);
    short*          wt     = (short*)carve((size_t)10 * DD * DD * 2);
    float*          inv    = (float*)carve(GG * 4);
    int*            off    = (int*)carve((NN + 1) * 4);
    int*            epos   = (int*)carve(NN * 4);
    int*            deg    = (int*)carve(NN * 4);
    unsigned*       e_info = (unsigned*)carve(((size_t)EE + 8 * NN) * 4);  // padded CSR
    int*            goff   = (int*)carve((GG + 1) * 4);
    int*            bsum   = (int*)carve(256 * 4);
    int*            bpref  = (int*)carve(256 * 4);

    hipMemsetAsync(deg, 0, NN * sizeof(int), stream);
    hipMemsetAsync(out, 0, (size_t)GG * OO * sizeof(float), stream);

    const int NB = (NN + 255) / 256;   // 196

    // prep (independent of CSR build)
    cvt_x<<<(NN * DD / 2 + 255) / 256, 256, 0, stream>>>(x_in, (unsigned*)xb);
    build_combo<<<LL * CPAD, 128, 0, stream>>>(bond, combo);
    prep_wt<<<(10 * DD * DD + 255) / 256, 256, 0, stream>>>(conv_w1, conv_w2, wt);

    // CSR build (padded)
    deg_kernel<<<(EE + 255) / 256, 256, 0, stream>>>(ei, deg);
    bsum_kernel<<<NB, 256, 0, stream>>>(deg, bsum);
    scan_bsum<<<1, 256, 0, stream>>>(bsum, bpref, NB);
    emit_off<<<NB, 256, 0, stream>>>(deg, bpref, off, epos);
    goff_inv<<<1, 256, 0, stream>>>(batch, goff, inv);
    scatter_edges<<<(EE + 255) / 256, 256, 0, stream>>>(ei, eattr, epos, e_info);
    pad_fill<<<NB, 256, 0, stream>>>(off, deg, e_info);

    // layer-0 head on raw input x (fp32, unrounded)
    pool_head_f32<<<GG, 512, 0, stream>>>(x_in, goff, inv, fcw, fcb, out);

    const int conv_blocks = (NN + 63) / 64;     // 782
    const int aggr_blocks = (NN + 3) / 4;
    for (int i = 0; i < LL; ++i) {
        aggr_csr<<<aggr_blocks, 256, 0, stream>>>(
            xb, off, e_info, combo + (size_t)i * CPAD * DD, hin);
        conv_fused<<<conv_blocks, 256, 0, stream>>>(
            hin, wt + (size_t)i * DD * DD, wt + (size_t)(5 + i) * DD * DD,
            conv_b1 + (size_t)i * DD, cbg + (size_t)i * DD, cbb + (size_t)i * DD,
            cbm + (size_t)i * DD, cbv + (size_t)i * DD,
            conv_b2 + (size_t)i * DD, bg + (size_t)i * DD, bb + (size_t)i * DD,
            bm + (size_t)i * DD, bv + (size_t)i * DD, xb);
        pool_head_bf<<<GG, 512, 0, stream>>>(
            xb, goff, inv, fcw + (size_t)(i + 1) * DD * OO, fcb + (size_t)(i + 1) * OO, out);
    }
}

// Round 6
// 456.553 us; speedup vs baseline: 14.8747x; 1.0918x over previous
//
#include <hip/hip_runtime.h>

#define NN 50000
#define EE 600000
#define DD 128
#define GG 256
#define LL 5
#define OO 10
#define BN_EPS 1e-5f
#define CPAD 513   // 512 combos + 1 sentinel (-1e30) row per layer

// prep kernel block-range sizes
#define B_CVT   3125                       // NN*DD/8 / 256
#define B_COMBO 1283                       // ceil(LL*CPAD*DD / 256)
#define B_WT    640                        // 10*DD*DD / 256
#define B_DEG   2344                       // ceil(EE/256)
#define B_INV   1
#define B_POOL0 391                        // ceil(NN/128)
#define B_PREP  (B_CVT + B_COMBO + B_WT + B_DEG + B_INV + B_POOL0)

typedef __attribute__((ext_vector_type(8))) short short8;
typedef __attribute__((ext_vector_type(16))) float float16;

__device__ __forceinline__ unsigned short f2b(float f) {   // fp32 -> bf16 RNE
    unsigned u = __float_as_uint(f);
    unsigned r = u + 0x7FFFu + ((u >> 16) & 1u);
    return (unsigned short)(r >> 16);
}
__device__ __forceinline__ float blo(unsigned u) { return __uint_as_float(u << 16); }
__device__ __forceinline__ float bhi(unsigned u) { return __uint_as_float(u & 0xFFFF0000u); }

// ================= mega prep: cvt_x | combo | Wt | deg | inv | pool0 =================
__launch_bounds__(256)
__global__ void prep(const float* __restrict__ x, const int* __restrict__ ei,
                     const int* __restrict__ batch, const float* __restrict__ bond,
                     const float* __restrict__ w1, const float* __restrict__ w2,
                     unsigned* __restrict__ xb4, unsigned short* __restrict__ combo,
                     short* __restrict__ wt, int* __restrict__ deg,
                     float* __restrict__ inv, float* __restrict__ pooled0) {
    const int bid = blockIdx.x, t = threadIdx.x;
    if (bid < B_CVT) {
        // x (fp32) -> xb (bf16), 8 elems/thread
        int gid = bid * 256 + t;                          // uint4 units
        const float4* xp = (const float4*)(x + (size_t)gid * 8);
        float4 a = xp[0], b = xp[1];
        uint4 o;
        o.x = (unsigned)f2b(a.x) | ((unsigned)f2b(a.y) << 16);
        o.y = (unsigned)f2b(a.z) | ((unsigned)f2b(a.w) << 16);
        o.z = (unsigned)f2b(b.x) | ((unsigned)f2b(b.y) << 16);
        o.w = (unsigned)f2b(b.z) | ((unsigned)f2b(b.w) << 16);
        ((uint4*)xb4)[gid] = o;
    } else if (bid < B_CVT + B_COMBO) {
        int e = (bid - B_CVT) * 256 + t;
        if (e < LL * CPAD * DD) {
            int l = e / (CPAD * DD), rem = e - l * (CPAD * DD);
            int c = rem / DD, d = rem - c * DD;
            float s;
            if (c == 512) s = -1e30f;                     // sentinel: relu(x+s)==0
            else {
                const float* b_ = bond + (size_t)l * 3 * 8 * DD;
                s = b_[(c & 7) * DD + d] + b_[(8 + ((c >> 3) & 7)) * DD + d]
                  + b_[(16 + (c >> 6)) * DD + d];
            }
            combo[e] = f2b(s);
        }
    } else if (bid < B_CVT + B_COMBO + B_WT) {
        int idx = (bid - B_CVT - B_COMBO) * 256 + t;      // exact 10*16384
        int mat = idx >> 14, e2 = idx & 16383;
        int c = e2 >> 7, k = e2 & 127;
        const float* W = (mat < 5) ? (w1 + (size_t)mat * DD * DD)
                                   : (w2 + (size_t)(mat - 5) * DD * DD);
        wt[idx] = (short)f2b(W[k * DD + c]);
    } else if (bid < B_CVT + B_COMBO + B_WT + B_DEG) {
        int e = (bid - B_CVT - B_COMBO - B_WT) * 256 + t;
        if (e < EE) atomicAdd(&deg[ei[EE + e]], 1);
    } else if (bid < B_CVT + B_COMBO + B_WT + B_DEG + B_INV) {
        // inv[g] via binary search on sorted batch
        __shared__ int sg[GG + 1];
        int g = t, lo = 0, hi = NN;
        while (lo < hi) { int m = (lo + hi) >> 1; if (batch[m] < g) lo = m + 1; else hi = m; }
        sg[g] = lo;
        if (g == 0) sg[GG] = NN;
        __syncthreads();
        inv[g] = 1.0f / fmaxf((float)(sg[g + 1] - sg[g]), 1.0f);
    } else {
        // layer-0 pooling of raw fp32 x: 128 nodes/block, per-graph partials
        int b = bid - (B_CVT + B_COMBO + B_WT + B_DEG + B_INV);
        int n0 = b * 128;
        __shared__ int sb[128];
        __shared__ float part[4][DD];
        if (t < 128) { int row = n0 + t; sb[t] = (row < NN) ? batch[row] : -1; }
        ((float*)part)[t] = 0.f;
        ((float*)part)[t + 256] = 0.f;
        __syncthreads();
        int gmin = sb[0];
        int col = t & 127, rh = t >> 7;
        float pg[4] = {0.f, 0.f, 0.f, 0.f};
        for (int r = rh; r < 128; r += 2) {
            int s = sb[r];
            float v = (s >= 0) ? x[(size_t)(n0 + r) * DD + col] : 0.f;
            int dg = s - gmin;
#pragma unroll
            for (int j = 0; j < 4; ++j) pg[j] += (dg == j) ? v : 0.f;
        }
#pragma unroll
        for (int j = 0; j < 4; ++j)
            if (pg[j] != 0.f) atomicAdd(&part[j][col], pg[j]);
        __syncthreads();
        for (int q = t; q < 4 * DD; q += 256) {
            int j = q >> 7, c2 = q & 127;
            float v = part[j][c2];
            if (v != 0.f && gmin + j < GG) atomicAdd(&pooled0[(gmin + j) * DD + c2], v);
        }
    }
}

// ================= CSR allocation (order-free) + sentinel pad fill =================
__launch_bounds__(256)
__global__ void alloc_csr(const int* __restrict__ deg, int* __restrict__ cnt,
                          int* __restrict__ off, int* __restrict__ pend,
                          int* __restrict__ epos, unsigned* __restrict__ e_info) {
    int n = blockIdx.x * 256 + threadIdx.x;
    if (n >= NN) return;
    int d = deg[n];
    int pd = (d + 7) & ~7;
    int base = atomicAdd(cnt, pd);
    off[n] = base; epos[n] = base; pend[n] = base + pd;
    for (int i = base + d; i < base + pd; ++i) e_info[i] = (512u << 16);
}

// payload: src (16b) | combo index (10b) << 16
__launch_bounds__(256)
__global__ void scatter_edges(const int* __restrict__ ei, const int* __restrict__ eattr,
                              int* __restrict__ epos, unsigned* __restrict__ e_info) {
    int e = blockIdx.x * 256 + threadIdx.x;
    if (e >= EE) return;
    int dst = ei[EE + e];
    int pos = atomicAdd(&epos[dst], 1);
    unsigned cidx = (unsigned)eattr[e * 3 + 0] | ((unsigned)eattr[e * 3 + 1] << 3)
                  | ((unsigned)eattr[e * 3 + 2] << 6);
    e_info[pos] = (unsigned)ei[e] | (cidx << 16);
}

// ================= CSR aggregation + residual, 8-edge batched =================
__launch_bounds__(256)
__global__ void aggr_csr(const unsigned short* __restrict__ xb, const int* __restrict__ off,
                         const int* __restrict__ pend, const unsigned* __restrict__ e_info,
                         const unsigned short* __restrict__ combo,
                         unsigned short* __restrict__ hin) {
    int node = blockIdx.x * 4 + (threadIdx.x >> 6);
    int lane = threadIdx.x & 63;
    if (node >= NN) return;
    int p = off[node], pe = pend[node];
    int d = lane * 2;
    unsigned self = *(const unsigned*)&xb[(size_t)node * DD + d];
    float ax = blo(self), ay = bhi(self);
    for (; p < pe; p += 8) {
        unsigned infv[8], xr[8], cr[8];
#pragma unroll
        for (int j = 0; j < 8; ++j) infv[j] = e_info[p + j];
#pragma unroll
        for (int j = 0; j < 8; ++j) {
            xr[j] = *(const unsigned*)&xb[(size_t)(infv[j] & 0xFFFFu) * DD + d];
            cr[j] = *(const unsigned*)&combo[(size_t)(infv[j] >> 16) * DD + d];
        }
#pragma unroll
        for (int j = 0; j < 8; ++j) {
            ax += fmaxf(blo(xr[j]) + blo(cr[j]), 0.f);
            ay += fmaxf(bhi(xr[j]) + bhi(cr[j]), 0.f);
        }
    }
    *(unsigned*)&hin[(size_t)node * DD + d] = (unsigned)f2b(ax) | ((unsigned)f2b(ay) << 16);
}

// ========== fused conv + pooling epilogue: relu(bn2(relu(bn1(h@W1+b1))@W2+b2)) ==========
__launch_bounds__(256)
__global__ void conv_fused(const unsigned short* __restrict__ hin,
                           const short* __restrict__ Wt1, const short* __restrict__ Wt2,
                           const float* __restrict__ b1, const float* __restrict__ g1,
                           const float* __restrict__ be1, const float* __restrict__ m1,
                           const float* __restrict__ v1,
                           const float* __restrict__ b2, const float* __restrict__ g2,
                           const float* __restrict__ be2, const float* __restrict__ m2,
                           const float* __restrict__ v2,
                           const int* __restrict__ batch,
                           unsigned short* __restrict__ outb,
                           float* __restrict__ pool_slot) {
    __shared__ short As[64 * 136];
    __shared__ int sbg[64];                 // batch[row]-gmin, or -1 if row OOB
    const int tid  = threadIdx.x;
    const int lane = tid & 63;
    const int wave = tid >> 6;
    const int row0 = blockIdx.x * 64;

    const int col   = wave * 32 + (lane & 31);
    const int khalf = (lane >> 5) * 8;
    const int arow  = lane & 31;
    const int rbase = 4 * (lane >> 5);
    const int gmin  = batch[row0];

    short8 bf[8];
#pragma unroll
    for (int ch = 0; ch < 8; ++ch)
        bf[ch] = *(const short8*)&Wt1[col * DD + ch * 16 + khalf];

    const float sc1 = g1[col] * rsqrtf(v1[col] + BN_EPS);
    const float sh1 = fmaf(b1[col] - m1[col], sc1, be1[col]);
    const float sc2 = g2[col] * rsqrtf(v2[col] + BN_EPS);
    const float sh2 = fmaf(b2[col] - m2[col], sc2, be2[col]);

    if (tid < 64) {
        int row = row0 + tid;
        sbg[tid] = (row < NN) ? batch[row] - gmin : -1;
    }
    for (int i = tid; i < 1024; i += 256) {
        int r = i >> 4, c8 = (i & 15) * 8;
        int row = row0 + r;
        uint4 z = make_uint4(0, 0, 0, 0);
        if (row < NN) z = *(const uint4*)&hin[(size_t)row * DD + c8];
        *(uint4*)&As[r * 136 + c8] = z;
    }
    __syncthreads();

    float16 acc0 = {0.f,0.f,0.f,0.f,0.f,0.f,0.f,0.f,0.f,0.f,0.f,0.f,0.f,0.f,0.f,0.f};
    float16 acc1 = acc0;
#pragma unroll
    for (int ch = 0; ch < 8; ++ch) {
        short8 a0 = *(const short8*)&As[(arow     ) * 136 + ch * 16 + khalf];
        short8 a1 = *(const short8*)&As[(32 + arow) * 136 + ch * 16 + khalf];
        acc0 = __builtin_amdgcn_mfma_f32_32x32x16_bf16(a0, bf[ch], acc0, 0, 0, 0);
        acc1 = __builtin_amdgcn_mfma_f32_32x32x16_bf16(a1, bf[ch], acc1, 0, 0, 0);
    }

#pragma unroll
    for (int ch = 0; ch < 8; ++ch)
        bf[ch] = *(const short8*)&Wt2[col * DD + ch * 16 + khalf];

    __syncthreads();
#pragma unroll
    for (int r = 0; r < 16; ++r) {
        int rl = (r & 3) + 8 * (r >> 2) + rbase;
        As[rl * 136 + col]        = (short)f2b(fmaxf(fmaf(acc0[r], sc1, sh1), 0.f));
        As[(32 + rl) * 136 + col] = (short)f2b(fmaxf(fmaf(acc1[r], sc1, sh1), 0.f));
    }
    __syncthreads();

    acc0 = acc1 = float16{0.f,0.f,0.f,0.f,0.f,0.f,0.f,0.f,0.f,0.f,0.f,0.f,0.f,0.f,0.f,0.f};
#pragma unroll
    for (int ch = 0; ch < 8; ++ch) {
        short8 a0 = *(const short8*)&As[(arow     ) * 136 + ch * 16 + khalf];
        short8 a1 = *(const short8*)&As[(32 + arow) * 136 + ch * 16 + khalf];
        acc0 = __builtin_amdgcn_mfma_f32_32x32x16_bf16(a0, bf[ch], acc0, 0, 0, 0);
        acc1 = __builtin_amdgcn_mfma_f32_32x32x16_bf16(a1, bf[ch], acc1, 0, 0, 0);
    }

    float pg0 = 0.f, pg1 = 0.f, pg2 = 0.f, pg3 = 0.f;
#pragma unroll
    for (int r = 0; r < 16; ++r) {
        int rl  = (r & 3) + 8 * (r >> 2) + rbase;
        int row = row0 + rl;
        float v0 = fmaxf(fmaf(acc0[r], sc2, sh2), 0.f);
        float v1_ = fmaxf(fmaf(acc1[r], sc2, sh2), 0.f);
        if (row < NN)      outb[(size_t)row * DD + col]        = f2b(v0);
        if (row + 32 < NN) outb[(size_t)(row + 32) * DD + col] = f2b(v1_);
        int ga = sbg[rl], gb = sbg[rl + 32];
        pg0 += ((ga == 0) ? v0 : 0.f) + ((gb == 0) ? v1_ : 0.f);
        pg1 += ((ga == 1) ? v0 : 0.f) + ((gb == 1) ? v1_ : 0.f);
        pg2 += ((ga == 2) ? v0 : 0.f) + ((gb == 2) ? v1_ : 0.f);
        pg3 += ((ga == 3) ? v0 : 0.f) + ((gb == 3) ? v1_ : 0.f);
    }
    pg0 += __shfl_down(pg0, 32);
    pg1 += __shfl_down(pg1, 32);
    pg2 += __shfl_down(pg2, 32);
    pg3 += __shfl_down(pg3, 32);
    if (lane < 32) {
        if (pg0 != 0.f)                 atomicAdd(&pool_slot[(gmin    ) * DD + col], pg0);
        if (pg1 != 0.f && gmin + 1 < GG) atomicAdd(&pool_slot[(gmin + 1) * DD + col], pg1);
        if (pg2 != 0.f && gmin + 2 < GG) atomicAdd(&pool_slot[(gmin + 2) * DD + col], pg2);
        if (pg3 != 0.f && gmin + 3 < GG) atomicAdd(&pool_slot[(gmin + 3) * DD + col], pg3);
    }
}

// ================= final head: out[g,:] = inv[g]*sum_l pooled_l@fcw_l + sum_l fcb_l =================
__launch_bounds__(64)
__global__ void head(const float* __restrict__ pooled, const float* __restrict__ inv,
                     const float* __restrict__ fcw, const float* __restrict__ fcb,
                     float* __restrict__ out) {
    int g = blockIdx.x, t = threadIdx.x;
    __shared__ float part[LL + 1][OO];
    if (t < (LL + 1) * OO) {
        int l = t / OO, o2 = t - l * OO;
        const float* p = pooled + ((size_t)l * GG + g) * DD;
        const float* w = fcw + (size_t)l * DD * OO + o2;
        float s = 0.f;
        for (int d2 = 0; d2 < DD; ++d2) s = fmaf(p[d2], w[(size_t)d2 * OO], s);
        part[l][o2] = s;
    }
    __syncthreads();
    if (t < OO) {
        float sp = 0.f, sb2 = 0.f;
#pragma unroll
        for (int l = 0; l < LL + 1; ++l) { sp += part[l][t]; sb2 += fcb[l * OO + t]; }
        out[g * OO + t] = sp * inv[g] + sb2;
    }
}

extern "C" void kernel_launch(void* const* d_in, const int* in_sizes, int n_in,
                              void* d_out, int out_size, void* d_ws, size_t ws_size,
                              hipStream_t stream) {
    const float* x_in    = (const float*)d_in[0];
    const int*   ei      = (const int*)d_in[1];
    const int*   eattr   = (const int*)d_in[2];
    const int*   batch   = (const int*)d_in[3];
    const float* bond    = (const float*)d_in[4];
    const float* conv_w1 = (const float*)d_in[5];
    const float* conv_b1 = (const float*)d_in[6];
    const float* cbg     = (const float*)d_in[7];
    const float* cbb     = (const float*)d_in[8];
    const float* cbm     = (const float*)d_in[9];
    const float* cbv     = (const float*)d_in[10];
    const float* conv_w2 = (const float*)d_in[11];
    const float* conv_b2 = (const float*)d_in[12];
    const float* bg      = (const float*)d_in[13];
    const float* bb      = (const float*)d_in[14];
    const float* bm      = (const float*)d_in[15];
    const float* bv      = (const float*)d_in[16];
    const float* fcw     = (const float*)d_in[17];
    const float* fcb     = (const float*)d_in[18];
    float* out = (float*)d_out;

    // ---- workspace carve-up (16B-aligned chunks) ----
    char* base = (char*)d_ws;
    size_t o = 0;
    auto carve = [&](size_t bytes) { void* p = base + o; o += (bytes + 15) & ~(size_t)15; return p; };
    unsigned short* xb     = (unsigned short*)carve((size_t)NN * DD * 2);
    unsigned short* hin    = (unsigned short*)carve((size_t)NN * DD * 2);
    unsigned short* combo  = (unsigned short*)carve((size_t)LL * CPAD * DD * 2);
    short*          wt     = (short*)carve((size_t)10 * DD * DD * 2);
    float*          inv    = (float*)carve(GG * 4);
    int*            off    = (int*)carve(NN * 4);
    int*            pend   = (int*)carve(NN * 4);
    int*            epos   = (int*)carve(NN * 4);
    unsigned*       e_info = (unsigned*)carve(((size_t)EE + 7 * NN) * 4);
    // contiguous zero-region: deg | cnt | pooled[6][G][D]
    const size_t ZBYTES = (size_t)NN * 4 + 16 + (size_t)(LL + 1) * GG * DD * 4;
    int*   deg    = (int*)carve(ZBYTES);
    int*   cnt    = (int*)((char*)deg + (size_t)NN * 4);
    float* pooled = (float*)((char*)cnt + 16);

    hipMemsetAsync(deg, 0, ZBYTES, stream);

    prep<<<B_PREP, 256, 0, stream>>>(x_in, ei, batch, bond, conv_w1, conv_w2,
                                     (unsigned*)xb, combo, wt, deg, inv, pooled);
    alloc_csr<<<(NN + 255) / 256, 256, 0, stream>>>(deg, cnt, off, pend, epos, e_info);
    scatter_edges<<<(EE + 255) / 256, 256, 0, stream>>>(ei, eattr, epos, e_info);

    const int conv_blocks = (NN + 63) / 64;     // 782
    const int aggr_blocks = (NN + 3) / 4;       // 12500
    for (int i = 0; i < LL; ++i) {
        aggr_csr<<<aggr_blocks, 256, 0, stream>>>(
            xb, off, pend, e_info, combo + (size_t)i * CPAD * DD, hin);
        conv_fused<<<conv_blocks, 256, 0, stream>>>(
            hin, wt + (size_t)i * DD * DD, wt + (size_t)(5 + i) * DD * DD,
            conv_b1 + (size_t)i * DD, cbg + (size_t)i * DD, cbb + (size_t)i * DD,
            cbm + (size_t)i * DD, cbv + (size_t)i * DD,
            conv_b2 + (size_t)i * DD, bg + (size_t)i * DD, bb + (size_t)i * DD,
            bm + (size_t)i * DD, bv + (size_t)i * DD,
            batch, xb, pooled + (size_t)(i + 1) * GG * DD);
    }
    head<<<GG, 64, 0, stream>>>(pooled, inv, fcw, fcb, out);
}